// Round 18
// baseline (249.911 us; speedup 1.0000x reference)
//
#include <hip/hip_runtime.h>
#include <hip/hip_bf16.h>

typedef unsigned short ush;
typedef unsigned int uint32;
typedef __attribute__((ext_vector_type(8))) short s8v;   // 8 bf16 (4 VGPRs)
typedef __attribute__((ext_vector_type(4))) float f4v;   // MFMA accumulator

#define NB 16
#define NT 128
#define NTM 128
#define NV 25
#define NCIN 64
#define NCM 256
#define NH 8
#define ND 32
#define NC 256
#define NK 3
#define NKC 768
#define LN_EPS 1e-6f
#define QSCALE 0.17677669529663687f

__device__ __forceinline__ float bf2f(ush u) {
    union { uint32 i; float f; } x; x.i = ((uint32)u) << 16; return x.f;
}
__device__ __forceinline__ ush f2bf(float f) {
    union { float f; uint32 i; } x; x.f = f;
    uint32 r = x.i + 0x7FFFu + ((x.i >> 16) & 1u);
    return (ush)(r >> 16);
}
__device__ __forceinline__ uint32 pack2(float a, float b) {
    return (uint32)f2bf(a) | ((uint32)f2bf(b) << 16);
}

// -------- dtype detector (f32 vs bf16 device buffers) --------
__global__ __launch_bounds__(256) void k_detect(const uint32* __restrict__ xw,
                                               int* __restrict__ flag)
{
    __shared__ int cnt;
    if (threadIdx.x == 0) cnt = 0;
    __syncthreads();
    int c = 0;
    for (int i = 0; i < 4; ++i) {
        uint32 u = xw[threadIdx.x + 256 * i];
        uint32 e = (u >> 7) & 0xFF;
        c += (e >= 100 && e <= 135) ? 1 : 0;
    }
    atomicAdd(&cnt, c);
    __syncthreads();
    if (threadIdx.x == 0) *flag = (cnt > 700) ? 1 : 0;   // 1 = bf16, 0 = f32
}

// A [k][v][w] -> A2 bf16 [32 w][96 kk], kk = k*32+v (pad w>=25, v>=25 with 0)
//             + cs4[w][4]: cs4[w*4+k] = sum_v A[k][v][w]
__global__ __launch_bounds__(256) void k_convA(const void* __restrict__ src,
                                               ush* __restrict__ A2,
                                               float* __restrict__ cs4,
                                               const int* __restrict__ flag)
{
    const bool isbf = (*flag != 0);
    const int tid = threadIdx.x;
    __shared__ float As[1875];
    for (int i = tid; i < 1875; i += 256)
        As[i] = isbf ? bf2f(((const ush*)src)[i]) : ((const float*)src)[i];
    __syncthreads();
    for (int j = tid; j < 32 * 96; j += 256) {
        int w = j / 96, kk = j - w * 96, k = kk >> 5, v = kk & 31;
        float val = (w < NV && v < NV) ? As[k * 625 + v * 25 + w] : 0.f;
        A2[j] = f2bf(val);
    }
    for (int j = tid; j < 100; j += 256) {
        int w = j >> 2, k = j & 3;
        float s = 0.f;
        if (k < 3)
            for (int v = 0; v < NV; ++v) s += As[k * 625 + v * 25 + w];
        cs4[j] = s;
    }
}

// -------- single-launch converter --------
struct CvEnt { const void* src; ush* dst; int n; int K; int N; int blk0; };
struct CvTab { CvEnt e[16]; };

__global__ __launch_bounds__(256) void k_convall(CvTab tab, const int* __restrict__ flag)
{
    const bool isbf = (*flag != 0);
    const int bi = (int)blockIdx.x;
    int ei = 0;
    #pragma unroll
    for (int i = 1; i < 16; ++i) if (bi >= tab.e[i].blk0) ei = i;
    const CvEnt& e = tab.e[ei];
    if (e.K == 0) {
        const int idx = (bi - e.blk0) * 2048 + (int)threadIdx.x * 8;
        if (idx >= e.n) return;
        if (isbf) {
            *(uint4*)&e.dst[idx] = *(const uint4*)((const ush*)e.src + idx);
        } else {
            const float* s = (const float*)e.src + idx;
            uint4 a = *(const uint4*)s;
            uint4 b = *(const uint4*)(s + 4);
            uint4 o;
            o.x = pack2(((float*)&a)[0], ((float*)&a)[1]);
            o.y = pack2(((float*)&a)[2], ((float*)&a)[3]);
            o.z = pack2(((float*)&b)[0], ((float*)&b)[1]);
            o.w = pack2(((float*)&b)[2], ((float*)&b)[3]);
            *(uint4*)&e.dst[idx] = o;
        }
    } else {
        const int s4 = (bi - e.blk0) * 1024 + (int)threadIdx.x * 4;
        if (s4 >= e.n) return;
        const int k = s4 / e.N, n0 = s4 - k * e.N;
        float v0, v1, v2, v3;
        if (isbf) {
            const ush* s = (const ush*)e.src + s4;
            v0 = bf2f(s[0]); v1 = bf2f(s[1]); v2 = bf2f(s[2]); v3 = bf2f(s[3]);
        } else {
            float4 f = *(const float4*)((const float*)e.src + s4);
            v0 = f.x; v1 = f.y; v2 = f.z; v3 = f.w;
        }
        ush* d = e.dst + (size_t)n0 * e.K + k;
        d[0] = f2bf(v0);
        d[e.K] = f2bf(v1);
        d[2 * e.K] = f2bf(v2);
        d[3 * e.K] = f2bf(v3);
    }
}

// XCD-aware bijective swizzle of the linear block index (requires nwg % 8 == 0)
__device__ __forceinline__ void xcd_swz(int& bx, int& by) {
    const int gx = gridDim.x, nwg = gx * gridDim.y;
    int lin = by * gx + bx;
    lin = (lin & 7) * (nwg >> 3) + (lin >> 3);
    bx = lin % gx;
    by = lin / gx;
}

// -------- MFMA GEMM: C[M, cols n0..] = A[M,K] @ Bt[N,K]^T --------
__global__ __launch_bounds__(256) void k_gemm(
    const ush* __restrict__ A, const ush* __restrict__ Bt, ush* __restrict__ C,
    int M, int K, int ldC)
{
    int bx = blockIdx.x, by = blockIdx.y;
    xcd_swz(bx, by);
    const int n0 = bx * 128, m0 = by * 128;
    const int tid = threadIdx.x, w = tid >> 6, l = tid & 63;
    __shared__ ush As[8192], Bs[8192];
    const char* AsB = (const char*)As;
    const char* BsB = (const char*)Bs;
    const int rl = l >> 3, cc = l & 7;
    f4v acc[4][4] = {};
    const int wm = w >> 1, wn = w & 1;

    for (int kt = 0; kt < K; kt += 64) {
        __syncthreads();
        #pragma unroll
        for (int j = 0; j < 4; ++j) {
            const int r = (w * 4 + j) * 8 + rl;
            const int sc = (cc ^ (r & 7)) * 8;
            const ush* ga = &A[(size_t)(m0 + r) * K + kt + sc];
            const ush* gb = &Bt[(size_t)(n0 + r) * K + kt + sc];
            __builtin_amdgcn_global_load_lds(
                (const __attribute__((address_space(1))) uint32*)ga,
                (__attribute__((address_space(3))) uint32*)&As[(w * 4 + j) * 512], 16, 0, 0);
            __builtin_amdgcn_global_load_lds(
                (const __attribute__((address_space(1))) uint32*)gb,
                (__attribute__((address_space(3))) uint32*)&Bs[(w * 4 + j) * 512], 16, 0, 0);
        }
        __syncthreads();
        #pragma unroll
        for (int ks = 0; ks < 2; ++ks) {
            const int ko = ks * 64 + (l >> 4) * 16;
            s8v a[4], b[4];
            #pragma unroll
            for (int mi = 0; mi < 4; ++mi) {
                const int ra = wm * 64 + mi * 16 + (l & 15);
                a[mi] = *(const s8v*)(AsB + ra * 128 + (ko ^ ((ra & 7) << 4)));
            }
            #pragma unroll
            for (int ni = 0; ni < 4; ++ni) {
                const int rb = wn * 64 + ni * 16 + (l & 15);
                b[ni] = *(const s8v*)(BsB + rb * 128 + (ko ^ ((rb & 7) << 4)));
            }
            #pragma unroll
            for (int mi = 0; mi < 4; ++mi)
                #pragma unroll
                for (int ni = 0; ni < 4; ++ni)
                    acc[mi][ni] = __builtin_amdgcn_mfma_f32_16x16x32_bf16(a[mi], b[ni],
                                                                          acc[mi][ni], 0, 0, 0);
        }
    }
    const int col = n0 + wn * 64 + (l & 15);
    #pragma unroll
    for (int mi = 0; mi < 4; ++mi) {
        const int row_base = m0 + wm * 64 + mi * 16 + (l >> 4) * 4;
        #pragma unroll
        for (int ni = 0; ni < 4; ++ni)
            #pragma unroll
            for (int r = 0; r < 4; ++r)
                C[(size_t)(row_base + r) * ldC + col + ni * 16] = f2bf(acc[mi][ni][r]);
    }
}

// -------- merged stage-2 GEMM: bx<2 -> q2 = h1@Wq2 ; bx>=2 -> kv2 = m@Wkv2 --------
__global__ __launch_bounds__(256) void k_gemm_s2(
    const ush* __restrict__ Aq, const ush* __restrict__ Akv,
    const ush* __restrict__ Btq, const ush* __restrict__ Btkv,
    ush* __restrict__ C, int M)
{
    int bx = blockIdx.x, by = blockIdx.y;
    xcd_swz(bx, by);
    const ush* A = (bx < 2) ? Aq : Akv;
    const ush* Bt = (bx < 2) ? (Btq + (size_t)(bx * 128) * NC)
                             : (Btkv + (size_t)((bx - 2) * 128) * NC);
    const int c0 = bx * 128, m0 = by * 128;
    const int K = NC, ldC = NKC;
    const int tid = threadIdx.x, w = tid >> 6, l = tid & 63;
    __shared__ ush As[8192], Bs[8192];
    const char* AsB = (const char*)As;
    const char* BsB = (const char*)Bs;
    const int rl = l >> 3, cc = l & 7;
    f4v acc[4][4] = {};
    const int wm = w >> 1, wn = w & 1;

    for (int kt = 0; kt < K; kt += 64) {
        __syncthreads();
        #pragma unroll
        for (int j = 0; j < 4; ++j) {
            const int r = (w * 4 + j) * 8 + rl;
            const int sc = (cc ^ (r & 7)) * 8;
            const ush* ga = &A[(size_t)(m0 + r) * K + kt + sc];
            const ush* gb = &Bt[(size_t)r * K + kt + sc];
            __builtin_amdgcn_global_load_lds(
                (const __attribute__((address_space(1))) uint32*)ga,
                (__attribute__((address_space(3))) uint32*)&As[(w * 4 + j) * 512], 16, 0, 0);
            __builtin_amdgcn_global_load_lds(
                (const __attribute__((address_space(1))) uint32*)gb,
                (__attribute__((address_space(3))) uint32*)&Bs[(w * 4 + j) * 512], 16, 0, 0);
        }
        __syncthreads();
        #pragma unroll
        for (int ks = 0; ks < 2; ++ks) {
            const int ko = ks * 64 + (l >> 4) * 16;
            s8v a[4], b[4];
            #pragma unroll
            for (int mi = 0; mi < 4; ++mi) {
                const int ra = wm * 64 + mi * 16 + (l & 15);
                a[mi] = *(const s8v*)(AsB + ra * 128 + (ko ^ ((ra & 7) << 4)));
            }
            #pragma unroll
            for (int ni = 0; ni < 4; ++ni) {
                const int rb = wn * 64 + ni * 16 + (l & 15);
                b[ni] = *(const s8v*)(BsB + rb * 128 + (ko ^ ((rb & 7) << 4)));
            }
            #pragma unroll
            for (int mi = 0; mi < 4; ++mi)
                #pragma unroll
                for (int ni = 0; ni < 4; ++ni)
                    acc[mi][ni] = __builtin_amdgcn_mfma_f32_16x16x32_bf16(a[mi], b[ni],
                                                                          acc[mi][ni], 0, 0, 0);
        }
    }
    const int col = c0 + wn * 64 + (l & 15);
    #pragma unroll
    for (int mi = 0; mi < 4; ++mi) {
        const int row_base = m0 + wm * 64 + mi * 16 + (l >> 4) * 4;
        #pragma unroll
        for (int ni = 0; ni < 4; ++ni)
            #pragma unroll
            for (int r = 0; r < 4; ++r)
                C[(size_t)(row_base + r) * ldC + col + ni * 16] = f2bf(acc[mi][ni][r]);
    }
}

// -------- MFMA attention: 8 waves = 2 heads x 4 t-quarters; K+V in LDS --------
// Finer t-split doubles resident-wave potential (32KB LDS -> 4-5 blocks/CU).
template<int MASKED>
__global__ __launch_bounds__(512) void k_attn_mfma(
    const ush* __restrict__ QKV, ush* __restrict__ O)
{
    const int v = blockIdx.x, hq = blockIdx.y, b = blockIdx.z;
    const int tid = threadIdx.x, wv = tid >> 6, l = tid & 63;
    const int hs = wv >> 2, th = wv & 3;
    const int h = hq * 2 + hs;
    const int g = l >> 4, c = l & 15;
    __shared__ ush Vs[2][NT * ND];   // 16 KB linear V (2 heads)
    __shared__ ush Ks[2][NT * ND];   // 16 KB swizzled K
    const size_t tokStride = (size_t)NV * NKC;
    const ush* base = QKV + ((size_t)b * NT * NV + v) * NKC;

    const int vrow = l >> 2, vch = (l & 3) * 8;
    #pragma unroll
    for (int i = 0; i < 2; ++i) {
        const int row = th * 32 + 16 * i + vrow;
        s8v rv = *(const s8v*)(base + (size_t)row * tokStride + 512 + h * ND + vch);
        *(s8v*)&Vs[hs][row * ND + vch] = rv;
        s8v rk = *(const s8v*)(base + (size_t)row * tokStride + 256 + h * ND + vch);
        const uint32 kb = ((uint32)(row * 64 + (l & 3) * 16)) ^ (((uint32)(row & 7)) << 4);
        *(s8v*)((char*)Ks[hs] + kb) = rk;
    }
    __syncthreads();
    // V^T fragments from LDS: vf[ks][ni][j] = V[32ks+8g+j][16ni+c]
    s8v vf[4][2];
    #pragma unroll
    for (int ks = 0; ks < 4; ++ks)
        #pragma unroll
        for (int ni = 0; ni < 2; ++ni) {
            s8v tmp;
            #pragma unroll
            for (int j = 0; j < 8; ++j)
                tmp[j] = (short)Vs[hs][(32 * ks + 8 * g + j) * ND + 16 * ni + c];
            vf[ks][ni] = tmp;
        }

    ush* og = O + ((size_t)b * NT * NV + v) * NC + h * ND;
    const int qoff = h * ND + g * 8;
    const int ga = (g & 1) * 2;
    const int l1 = ga * 16 + c, l2 = l1 + 16;
    const bool hisel = (g >> 1) != 0;
    const char* KsB = (const char*)Ks[hs];

    for (int i = 0; i < 2; ++i) {
        const int t16 = th * 2 + i;
        s8v qf = *(const s8v*)(base + (size_t)(16 * t16 + c) * tokStride + qoff);
        f4v st[8];
        #pragma unroll
        for (int si = 0; si < 8; ++si) {
            if (MASKED && si > t16) { st[si] = (f4v){0.f, 0.f, 0.f, 0.f}; continue; }
            const int krow = 16 * si + c;
            const uint32 rb = ((uint32)(krow * 64 + g * 16)) ^ (((uint32)(krow & 7)) << 4);
            s8v kf = *(const s8v*)(KsB + rb);
            st[si] = __builtin_amdgcn_mfma_f32_16x16x32_bf16(kf, qf,
                                                             (f4v){0.f, 0.f, 0.f, 0.f}, 0, 0, 0);
        }
        const int t = 16 * t16 + c;
        if (MASKED) {
            #pragma unroll
            for (int si = 0; si < 8; ++si) {
                if (si > t16) continue;
                #pragma unroll
                for (int r = 0; r < 4; ++r)
                    if (16 * si + 4 * g + r > t) st[si][r] = -1e30f;
            }
        }
        float mx = -1e30f;
        #pragma unroll
        for (int si = 0; si < 8; ++si) {
            if (MASKED && si > t16) continue;
            #pragma unroll
            for (int r = 0; r < 4; ++r) mx = fmaxf(mx, st[si][r]);
        }
        mx = fmaxf(mx, __shfl_xor(mx, 16));
        mx = fmaxf(mx, __shfl_xor(mx, 32));
        float sm = 0.f;
        #pragma unroll
        for (int si = 0; si < 8; ++si) {
            if (MASKED && si > t16) continue;
            #pragma unroll
            for (int r = 0; r < 4; ++r) {
                float e = __expf((st[si][r] - mx) * QSCALE);
                st[si][r] = e;
                sm += e;
            }
        }
        sm += __shfl_xor(sm, 16);
        sm += __shfl_xor(sm, 32);
        const float inv = 1.f / sm;
        uint32 u[8][2];
        #pragma unroll
        for (int si = 0; si < 8; ++si) {
            if (MASKED && si > t16) { u[si][0] = 0u; u[si][1] = 0u; continue; }
            float e0 = st[si][0] * inv, e1 = st[si][1] * inv;
            float e2 = st[si][2] * inv, e3 = st[si][3] * inv;
            asm("v_cvt_pk_bf16_f32 %0, %1, %2" : "=v"(u[si][0]) : "v"(e0), "v"(e1));
            asm("v_cvt_pk_bf16_f32 %0, %1, %2" : "=v"(u[si][1]) : "v"(e2), "v"(e3));
        }
        f4v o[2] = {};
        #pragma unroll
        for (int ks = 0; ks < 4; ++ks) {
            if (MASKED && 2 * ks > t16) continue;
            uint32 w0a = __shfl(u[2 * ks][0], l1),     w0b = __shfl(u[2 * ks][1], l1);
            uint32 w0c = __shfl(u[2 * ks][0], l2),     w0d = __shfl(u[2 * ks][1], l2);
            uint32 w1a = __shfl(u[2 * ks + 1][0], l1), w1b = __shfl(u[2 * ks + 1][1], l1);
            uint32 w1c = __shfl(u[2 * ks + 1][0], l2), w1d = __shfl(u[2 * ks + 1][1], l2);
            union { uint32 w[4]; s8v s; } pa;
            pa.w[0] = hisel ? w1a : w0a;
            pa.w[1] = hisel ? w1b : w0b;
            pa.w[2] = hisel ? w1c : w0c;
            pa.w[3] = hisel ? w1d : w0d;
            o[0] = __builtin_amdgcn_mfma_f32_16x16x32_bf16(pa.s, vf[ks][0], o[0], 0, 0, 0);
            o[1] = __builtin_amdgcn_mfma_f32_16x16x32_bf16(pa.s, vf[ks][1], o[1], 0, 0, 0);
        }
        #pragma unroll
        for (int ni = 0; ni < 2; ++ni)
            #pragma unroll
            for (int r = 0; r < 4; ++r)
                og[(size_t)(16 * t16 + 4 * g + r) * (NV * NC) + 16 * ni + c] = f2bf(o[ni][r]);
    }
}

// ---------------- row LayerNorm (unbiased std), in place, 1 wave = 1 row ----------------
__global__ __launch_bounds__(256) void k_ln(
    ush* __restrict__ buf, const ush* __restrict__ g, const ush* __restrict__ bb)
{
    const int row = blockIdx.x * 4 + (threadIdx.x >> 6);
    const int lane = threadIdx.x & 63;
    ush* p = buf + (size_t)row * NC + lane * 4;
    uint2 u = *(uint2*)p;
    float x0 = bf2f((ush)(u.x & 0xffff)), x1 = bf2f((ush)(u.x >> 16));
    float x2 = bf2f((ush)(u.y & 0xffff)), x3 = bf2f((ush)(u.y >> 16));
    float s = x0 + x1 + x2 + x3;
    float q = x0 * x0 + x1 * x1 + x2 * x2 + x3 * x3;
    #pragma unroll
    for (int o = 32; o; o >>= 1) { s += __shfl_xor(s, o); q += __shfl_xor(q, o); }
    float mean = s * (1.f / 256.f);
    float var = fmaxf((q - 256.f * mean * mean) * (1.f / 255.f), 0.f);
    float inv = 1.f / (sqrtf(var) + LN_EPS);
    float o0 = bf2f(g[lane * 4 + 0]) * (x0 - mean) * inv + bf2f(bb[lane * 4 + 0]);
    float o1 = bf2f(g[lane * 4 + 1]) * (x1 - mean) * inv + bf2f(bb[lane * 4 + 1]);
    float o2 = bf2f(g[lane * 4 + 2]) * (x2 - mean) * inv + bf2f(bb[lane * 4 + 2]);
    float o3 = bf2f(g[lane * 4 + 3]) * (x3 - mean) * inv + bf2f(bb[lane * 4 + 3]);
    uint32 lo = pack2(o0, o1);
    uint32 hi = pack2(o2, o3);
    *(uint2*)p = make_uint2(lo, hi);
}

// -------- GCN via MFMA: per (b,t): h3[32 w][256 c] = A2[32][96] @ X[96][256] --------
__global__ __launch_bounds__(256) void k_gcn_mfma(
    const ush* __restrict__ xw, const ush* __restrict__ A2,
    const float* __restrict__ cs4,
    const ush* __restrict__ bg, const ush* __restrict__ g3, const ush* __restrict__ b3,
    float* __restrict__ outp)
{
    const int t = blockIdx.x, b = blockIdx.y;
    const int tid = threadIdx.x;
    __shared__ uint4 Xs4[2400];                 // 38.4KB: X tile, swizzled
    char* Xs = (char*)Xs4;
    float* h3s = (float*)Xs4;                   // [25][260] f32 overlay after barrier
    const int l = tid & 63, wv = tid >> 6, g = l >> 4, c4 = l & 15;

    s8v af[2][3];
    #pragma unroll
    for (int mi = 0; mi < 2; ++mi)
        #pragma unroll
        for (int ks = 0; ks < 3; ++ks)
            af[mi][ks] = *(const s8v*)&A2[(mi * 16 + c4) * 96 + ks * 32 + g * 8];

    const ush* xr = xw + ((size_t)(b * NT + t)) * NV * NKC;
    for (int i = tid; i < 2400; i += 256) {
        int v = i / 96, c8 = i - v * 96;
        uint32 off = (uint32)(v * 1536 + c8 * 16) ^ (((v >> 3) & 3) << 4);
        *(uint4*)(Xs + off) = *(const uint4*)&xr[(size_t)v * NKC + c8 * 8];
    }
    __syncthreads();

    f4v acc[2][4] = {};
    const int c0 = wv * 64;
    #pragma unroll
    for (int ks = 0; ks < 3; ++ks) {
        #pragma unroll
        for (int ni = 0; ni < 4; ++ni) {
            const int c = c0 + ni * 16 + c4;
            s8v bfr;
            #pragma unroll
            for (int j = 0; j < 8; ++j) {
                int v = g * 8 + j; if (v > 24) v = 24;
                uint32 off = (uint32)(v * 1536 + ks * 512 + c * 2) ^ (((v >> 3) & 3) << 4);
                bfr[j] = *(const short*)(Xs + off);
            }
            acc[0][ni] = __builtin_amdgcn_mfma_f32_16x16x32_bf16(af[0][ks], bfr, acc[0][ni], 0, 0, 0);
            acc[1][ni] = __builtin_amdgcn_mfma_f32_16x16x32_bf16(af[1][ks], bfr, acc[1][ni], 0, 0, 0);
        }
    }
    __syncthreads();
    #pragma unroll
    for (int mi = 0; mi < 2; ++mi)
        #pragma unroll
        for (int r = 0; r < 4; ++r) {
            const int w = mi * 16 + g * 4 + r;
            if (w < NV) {
                #pragma unroll
                for (int ni = 0; ni < 4; ++ni)
                    h3s[w * 260 + c0 + ni * 16 + c4] = acc[mi][ni][r];
            }
        }
    __syncthreads();
    {
        const int lane = tid & 63;
        float bgq[3][4];
        #pragma unroll
        for (int k = 0; k < 3; ++k)
            #pragma unroll
            for (int i = 0; i < 4; ++i)
                bgq[k][i] = bf2f(bg[k * NC + lane * 4 + i]);
        for (int w = wv; w < NV; w += 4) {
            float4 xq = *(const float4*)&h3s[w * 260 + lane * 4];
            const float cw0 = cs4[w * 4], cw1 = cs4[w * 4 + 1], cw2 = cs4[w * 4 + 2];
            xq.x += cw0 * bgq[0][0] + cw1 * bgq[1][0] + cw2 * bgq[2][0];
            xq.y += cw0 * bgq[0][1] + cw1 * bgq[1][1] + cw2 * bgq[2][1];
            xq.z += cw0 * bgq[0][2] + cw1 * bgq[1][2] + cw2 * bgq[2][2];
            xq.w += cw0 * bgq[0][3] + cw1 * bgq[1][3] + cw2 * bgq[2][3];
            float s = xq.x + xq.y + xq.z + xq.w;
            float q = xq.x * xq.x + xq.y * xq.y + xq.z * xq.z + xq.w * xq.w;
            #pragma unroll
            for (int o = 32; o; o >>= 1) { s += __shfl_xor(s, o); q += __shfl_xor(q, o); }
            float mean = s * (1.f / 256.f);
            float var = fmaxf((q - 256.f * mean * mean) * (1.f / 255.f), 0.f);
            float inv = 1.f / (sqrtf(var) + LN_EPS);
            float o0 = bf2f(g3[lane * 4 + 0]) * (xq.x - mean) * inv + bf2f(b3[lane * 4 + 0]);
            float o1 = bf2f(g3[lane * 4 + 1]) * (xq.y - mean) * inv + bf2f(b3[lane * 4 + 1]);
            float o2 = bf2f(g3[lane * 4 + 2]) * (xq.z - mean) * inv + bf2f(b3[lane * 4 + 2]);
            float o3 = bf2f(g3[lane * 4 + 3]) * (xq.w - mean) * inv + bf2f(b3[lane * 4 + 3]);
            float* op = outp + (((size_t)(b * NT + t)) * NV + w) * NC + lane * 4;
            *(float4*)op = make_float4(o0, o1, o2, o3);
        }
    }
}

extern "C" void kernel_launch(void* const* d_in, const int* in_sizes, int n_in,
                              void* d_out, int out_size, void* d_ws, size_t ws_size,
                              hipStream_t stream)
{
    const size_t NTOK = (size_t)NB * NT * NV;   // 51200
    char* ws = (char*)d_ws;
    int* flag = (int*)ws;
    ush* A2 = (ush*)(ws + 256);                 // [32][96] bf16, 6KB
    float* cs4 = (float*)(ws + 256 + 6144);     // [25][4] f32, 400B
    ush* bufA = (ush*)(ws + 16384);             // [M,768]  78.6MB
    ush* bufB = bufA + NTOK * NKC;              // [M,256]  26.2MB
    ush* conv = bufB + NTOK * NC;

    k_detect<<<1, 256, 0, stream>>>((const uint32*)d_in[0], flag);
    k_convA<<<1, 256, 0, stream>>>(d_in[2], A2, cs4, flag);

    // ---- one-launch conversion table ----
    CvTab tab;
    int nent = 0, blk = 0;
    ush* p = conv;
    const ush* cp[18] = {};
    auto add = [&](int idx, int n, int K, int N, ush*& dst_out) {
        tab.e[nent] = { d_in[idx], p, n, K, N, blk };
        dst_out = p;
        blk += (K == 0) ? (n + 2047) / 2048 : (n + 1023) / 1024;
        p += (size_t)((n + 7) & ~7);
        ++nent;
    };
    ush* d;
    add(0, NB * NT * NV * NCIN, 0, 0, d);  cp[0] = d;
    add(1, NB * NTM * NV * NCM, 0, 0, d);  cp[1] = d;
    add(15, NKC, 0, 0, d);                 cp[15] = d;
    add(7, NC, 0, 0, d);  cp[7] = d;
    add(8, NC, 0, 0, d);  cp[8] = d;
    add(12, NC, 0, 0, d); cp[12] = d;
    add(13, NC, 0, 0, d); cp[13] = d;
    add(16, NC, 0, 0, d); cp[16] = d;
    add(17, NC, 0, 0, d); cp[17] = d;
    ush* w1t;
    add(4, NCIN * NC, NCIN, NC, w1t);      // [256][64] q
    add(5, NCIN * NC, NCIN, NC, d);        // k  (contiguous after q)
    add(6, NCIN * NC, NCIN, NC, d);        // v
    ush* wq2t;
    add(9, NC * NC, NC, NC, wq2t);         // [256][256]
    ush* wkv2t;
    add(10, NCM * NC, NCM, NC, wkv2t);     // [256][256] k
    add(11, NCM * NC, NCM, NC, d);         // v (contiguous)
    ush* wgt;
    add(14, NC * NKC, NC, NKC, wgt);       // [768][256]
    k_convall<<<blk, 256, 0, stream>>>(tab, flag);

    const int M = (int)NTOK;
    // stage 1: qkv1 = x @ [Wq1|Wk1|Wv1]  -> bufA [M,768]
    k_gemm<<<dim3(6, M / 128), 256, 0, stream>>>(cp[0], w1t, bufA, M, NCIN, NKC);
    k_attn_mfma<1><<<dim3(NV, NH / 2, NB), 512, 0, stream>>>(bufA, bufB);
    k_ln<<<M / 4, 256, 0, stream>>>(bufB, cp[7], cp[8]);
    // stage 2 (one launch): q2 = h1@Wq2 (cols 0-255) + kv2 = m@[Wk2|Wv2] (cols 256-767)
    k_gemm_s2<<<dim3(6, M / 128), 256, 0, stream>>>(bufB, cp[1], wq2t, wkv2t, bufA, M);
    k_attn_mfma<0><<<dim3(NV, NH / 2, NB), 512, 0, stream>>>(bufA, bufB);
    k_ln<<<M / 4, 256, 0, stream>>>(bufB, cp[12], cp[13]);
    // stage 3: xw = h2 @ Wg -> bufA [M,768]; then MFMA GCN + LN -> out
    k_gemm<<<dim3(6, M / 128), 256, 0, stream>>>(bufB, wgt, bufA, M, NC, NKC);
    k_gcn_mfma<<<dim3(NT, NB), 256, 0, stream>>>(bufA, A2, cs4, cp[15], cp[16], cp[17],
                                                 (float*)d_out);
}

// Round 19
// 245.514 us; speedup vs baseline: 1.0179x; 1.0179x over previous
//
#include <hip/hip_runtime.h>
#include <hip/hip_bf16.h>

typedef unsigned short ush;
typedef unsigned int uint32;
typedef __attribute__((ext_vector_type(8))) short s8v;   // 8 bf16 (4 VGPRs)
typedef __attribute__((ext_vector_type(4))) float f4v;   // MFMA accumulator

#define NB 16
#define NT 128
#define NTM 128
#define NV 25
#define NCIN 64
#define NCM 256
#define NH 8
#define ND 32
#define NC 256
#define NK 3
#define NKC 768
#define LN_EPS 1e-6f
#define QSCALE 0.17677669529663687f

__device__ __forceinline__ float bf2f(ush u) {
    union { uint32 i; float f; } x; x.i = ((uint32)u) << 16; return x.f;
}
__device__ __forceinline__ ush f2bf(float f) {
    union { float f; uint32 i; } x; x.f = f;
    uint32 r = x.i + 0x7FFFu + ((x.i >> 16) & 1u);
    return (ush)(r >> 16);
}
__device__ __forceinline__ uint32 pack2(float a, float b) {
    return (uint32)f2bf(a) | ((uint32)f2bf(b) << 16);
}

// -------- dtype detector (f32 vs bf16 device buffers) --------
__global__ __launch_bounds__(256) void k_detect(const uint32* __restrict__ xw,
                                               int* __restrict__ flag)
{
    __shared__ int cnt;
    if (threadIdx.x == 0) cnt = 0;
    __syncthreads();
    int c = 0;
    for (int i = 0; i < 4; ++i) {
        uint32 u = xw[threadIdx.x + 256 * i];
        uint32 e = (u >> 7) & 0xFF;
        c += (e >= 100 && e <= 135) ? 1 : 0;
    }
    atomicAdd(&cnt, c);
    __syncthreads();
    if (threadIdx.x == 0) *flag = (cnt > 700) ? 1 : 0;   // 1 = bf16, 0 = f32
}

// A [k][v][w] -> A2 bf16 [32 w][96 kk], kk = k*32+v (pad w>=25, v>=25 with 0)
//             + cs4[w][4]: cs4[w*4+k] = sum_v A[k][v][w]
__global__ __launch_bounds__(256) void k_convA(const void* __restrict__ src,
                                               ush* __restrict__ A2,
                                               float* __restrict__ cs4,
                                               const int* __restrict__ flag)
{
    const bool isbf = (*flag != 0);
    const int tid = threadIdx.x;
    __shared__ float As[1875];
    for (int i = tid; i < 1875; i += 256)
        As[i] = isbf ? bf2f(((const ush*)src)[i]) : ((const float*)src)[i];
    __syncthreads();
    for (int j = tid; j < 32 * 96; j += 256) {
        int w = j / 96, kk = j - w * 96, k = kk >> 5, v = kk & 31;
        float val = (w < NV && v < NV) ? As[k * 625 + v * 25 + w] : 0.f;
        A2[j] = f2bf(val);
    }
    for (int j = tid; j < 100; j += 256) {
        int w = j >> 2, k = j & 3;
        float s = 0.f;
        if (k < 3)
            for (int v = 0; v < NV; ++v) s += As[k * 625 + v * 25 + w];
        cs4[j] = s;
    }
}

// -------- single-launch converter --------
struct CvEnt { const void* src; ush* dst; int n; int K; int N; int blk0; };
struct CvTab { CvEnt e[16]; };

__global__ __launch_bounds__(256) void k_convall(CvTab tab, const int* __restrict__ flag)
{
    const bool isbf = (*flag != 0);
    const int bi = (int)blockIdx.x;
    int ei = 0;
    #pragma unroll
    for (int i = 1; i < 16; ++i) if (bi >= tab.e[i].blk0) ei = i;
    const CvEnt& e = tab.e[ei];
    if (e.K == 0) {
        const int idx = (bi - e.blk0) * 2048 + (int)threadIdx.x * 8;
        if (idx >= e.n) return;
        if (isbf) {
            *(uint4*)&e.dst[idx] = *(const uint4*)((const ush*)e.src + idx);
        } else {
            const float* s = (const float*)e.src + idx;
            uint4 a = *(const uint4*)s;
            uint4 b = *(const uint4*)(s + 4);
            uint4 o;
            o.x = pack2(((float*)&a)[0], ((float*)&a)[1]);
            o.y = pack2(((float*)&a)[2], ((float*)&a)[3]);
            o.z = pack2(((float*)&b)[0], ((float*)&b)[1]);
            o.w = pack2(((float*)&b)[2], ((float*)&b)[3]);
            *(uint4*)&e.dst[idx] = o;
        }
    } else {
        const int s4 = (bi - e.blk0) * 1024 + (int)threadIdx.x * 4;
        if (s4 >= e.n) return;
        const int k = s4 / e.N, n0 = s4 - k * e.N;
        float v0, v1, v2, v3;
        if (isbf) {
            const ush* s = (const ush*)e.src + s4;
            v0 = bf2f(s[0]); v1 = bf2f(s[1]); v2 = bf2f(s[2]); v3 = bf2f(s[3]);
        } else {
            float4 f = *(const float4*)((const float*)e.src + s4);
            v0 = f.x; v1 = f.y; v2 = f.z; v3 = f.w;
        }
        ush* d = e.dst + (size_t)n0 * e.K + k;
        d[0] = f2bf(v0);
        d[e.K] = f2bf(v1);
        d[2 * e.K] = f2bf(v2);
        d[3 * e.K] = f2bf(v3);
    }
}

// XCD-aware bijective swizzle of the linear block index (requires nwg % 8 == 0)
__device__ __forceinline__ void xcd_swz(int& bx, int& by) {
    const int gx = gridDim.x, nwg = gx * gridDim.y;
    int lin = by * gx + bx;
    lin = (lin & 7) * (nwg >> 3) + (lin >> 3);
    bx = lin % gx;
    by = lin / gx;
}

// -------- MFMA GEMM: C[M, cols n0..] = A[M,K] @ Bt[N,K]^T --------
__global__ __launch_bounds__(256) void k_gemm(
    const ush* __restrict__ A, const ush* __restrict__ Bt, ush* __restrict__ C,
    int M, int K, int ldC)
{
    int bx = blockIdx.x, by = blockIdx.y;
    xcd_swz(bx, by);
    const int n0 = bx * 128, m0 = by * 128;
    const int tid = threadIdx.x, w = tid >> 6, l = tid & 63;
    __shared__ ush As[8192], Bs[8192];
    const char* AsB = (const char*)As;
    const char* BsB = (const char*)Bs;
    const int rl = l >> 3, cc = l & 7;
    f4v acc[4][4] = {};
    const int wm = w >> 1, wn = w & 1;

    for (int kt = 0; kt < K; kt += 64) {
        __syncthreads();
        #pragma unroll
        for (int j = 0; j < 4; ++j) {
            const int r = (w * 4 + j) * 8 + rl;
            const int sc = (cc ^ (r & 7)) * 8;
            const ush* ga = &A[(size_t)(m0 + r) * K + kt + sc];
            const ush* gb = &Bt[(size_t)(n0 + r) * K + kt + sc];
            __builtin_amdgcn_global_load_lds(
                (const __attribute__((address_space(1))) uint32*)ga,
                (__attribute__((address_space(3))) uint32*)&As[(w * 4 + j) * 512], 16, 0, 0);
            __builtin_amdgcn_global_load_lds(
                (const __attribute__((address_space(1))) uint32*)gb,
                (__attribute__((address_space(3))) uint32*)&Bs[(w * 4 + j) * 512], 16, 0, 0);
        }
        __syncthreads();
        #pragma unroll
        for (int ks = 0; ks < 2; ++ks) {
            const int ko = ks * 64 + (l >> 4) * 16;
            s8v a[4], b[4];
            #pragma unroll
            for (int mi = 0; mi < 4; ++mi) {
                const int ra = wm * 64 + mi * 16 + (l & 15);
                a[mi] = *(const s8v*)(AsB + ra * 128 + (ko ^ ((ra & 7) << 4)));
            }
            #pragma unroll
            for (int ni = 0; ni < 4; ++ni) {
                const int rb = wn * 64 + ni * 16 + (l & 15);
                b[ni] = *(const s8v*)(BsB + rb * 128 + (ko ^ ((rb & 7) << 4)));
            }
            #pragma unroll
            for (int mi = 0; mi < 4; ++mi)
                #pragma unroll
                for (int ni = 0; ni < 4; ++ni)
                    acc[mi][ni] = __builtin_amdgcn_mfma_f32_16x16x32_bf16(a[mi], b[ni],
                                                                          acc[mi][ni], 0, 0, 0);
        }
    }
    const int col = n0 + wn * 64 + (l & 15);
    #pragma unroll
    for (int mi = 0; mi < 4; ++mi) {
        const int row_base = m0 + wm * 64 + mi * 16 + (l >> 4) * 4;
        #pragma unroll
        for (int ni = 0; ni < 4; ++ni)
            #pragma unroll
            for (int r = 0; r < 4; ++r)
                C[(size_t)(row_base + r) * ldC + col + ni * 16] = f2bf(acc[mi][ni][r]);
    }
}

// -------- merged stage-2 GEMM: bx<2 -> q2 = h1@Wq2 ; bx>=2 -> kv2 = m@Wkv2 --------
__global__ __launch_bounds__(256) void k_gemm_s2(
    const ush* __restrict__ Aq, const ush* __restrict__ Akv,
    const ush* __restrict__ Btq, const ush* __restrict__ Btkv,
    ush* __restrict__ C, int M)
{
    int bx = blockIdx.x, by = blockIdx.y;
    xcd_swz(bx, by);
    const ush* A = (bx < 2) ? Aq : Akv;
    const ush* Bt = (bx < 2) ? (Btq + (size_t)(bx * 128) * NC)
                             : (Btkv + (size_t)((bx - 2) * 128) * NC);
    const int c0 = bx * 128, m0 = by * 128;
    const int K = NC, ldC = NKC;
    const int tid = threadIdx.x, w = tid >> 6, l = tid & 63;
    __shared__ ush As[8192], Bs[8192];
    const char* AsB = (const char*)As;
    const char* BsB = (const char*)Bs;
    const int rl = l >> 3, cc = l & 7;
    f4v acc[4][4] = {};
    const int wm = w >> 1, wn = w & 1;

    for (int kt = 0; kt < K; kt += 64) {
        __syncthreads();
        #pragma unroll
        for (int j = 0; j < 4; ++j) {
            const int r = (w * 4 + j) * 8 + rl;
            const int sc = (cc ^ (r & 7)) * 8;
            const ush* ga = &A[(size_t)(m0 + r) * K + kt + sc];
            const ush* gb = &Bt[(size_t)r * K + kt + sc];
            __builtin_amdgcn_global_load_lds(
                (const __attribute__((address_space(1))) uint32*)ga,
                (__attribute__((address_space(3))) uint32*)&As[(w * 4 + j) * 512], 16, 0, 0);
            __builtin_amdgcn_global_load_lds(
                (const __attribute__((address_space(1))) uint32*)gb,
                (__attribute__((address_space(3))) uint32*)&Bs[(w * 4 + j) * 512], 16, 0, 0);
        }
        __syncthreads();
        #pragma unroll
        for (int ks = 0; ks < 2; ++ks) {
            const int ko = ks * 64 + (l >> 4) * 16;
            s8v a[4], b[4];
            #pragma unroll
            for (int mi = 0; mi < 4; ++mi) {
                const int ra = wm * 64 + mi * 16 + (l & 15);
                a[mi] = *(const s8v*)(AsB + ra * 128 + (ko ^ ((ra & 7) << 4)));
            }
            #pragma unroll
            for (int ni = 0; ni < 4; ++ni) {
                const int rb = wn * 64 + ni * 16 + (l & 15);
                b[ni] = *(const s8v*)(BsB + rb * 128 + (ko ^ ((rb & 7) << 4)));
            }
            #pragma unroll
            for (int mi = 0; mi < 4; ++mi)
                #pragma unroll
                for (int ni = 0; ni < 4; ++ni)
                    acc[mi][ni] = __builtin_amdgcn_mfma_f32_16x16x32_bf16(a[mi], b[ni],
                                                                          acc[mi][ni], 0, 0, 0);
        }
    }
    const int col = c0 + wn * 64 + (l & 15);
    #pragma unroll
    for (int mi = 0; mi < 4; ++mi) {
        const int row_base = m0 + wm * 64 + mi * 16 + (l >> 4) * 4;
        #pragma unroll
        for (int ni = 0; ni < 4; ++ni)
            #pragma unroll
            for (int r = 0; r < 4; ++r)
                C[(size_t)(row_base + r) * ldC + col + ni * 16] = f2bf(acc[mi][ni][r]);
    }
}

// -------- MFMA attention: 8 waves = 4 heads x 2 t-halves; K+V in LDS --------
// launch_bounds(512,4): LDS caps at 2 blocks/CU = 4 waves/SIMD -> allow 128 VGPR
// so the compiler can pipeline across the 4 unrolled t16 iterations.
// All 4 qf loads hoisted before the loop (removes global latency from the chain).
template<int MASKED>
__global__ __launch_bounds__(512, 4) void k_attn_mfma(
    const ush* __restrict__ QKV, ush* __restrict__ O)
{
    const int v = blockIdx.x, hq = blockIdx.y, b = blockIdx.z;
    const int tid = threadIdx.x, wv = tid >> 6, l = tid & 63;
    const int hs = wv >> 1, th = wv & 1;
    const int h = hq * 4 + hs;
    const int g = l >> 4, c = l & 15;
    __shared__ ush Vs[4][NT * ND];   // 32 KB linear V
    __shared__ ush Ks[4][NT * ND];   // 32 KB swizzled K
    const size_t tokStride = (size_t)NV * NKC;
    const ush* base = QKV + ((size_t)b * NT * NV + v) * NKC;

    const int vrow = l >> 2, vch = (l & 3) * 8;
    #pragma unroll
    for (int i = 0; i < 4; ++i) {
        const int row = 16 * (4 * th + i) + vrow;
        s8v rv = *(const s8v*)(base + (size_t)row * tokStride + 512 + h * ND + vch);
        *(s8v*)&Vs[hs][row * ND + vch] = rv;
        s8v rk = *(const s8v*)(base + (size_t)row * tokStride + 256 + h * ND + vch);
        const uint32 kb = ((uint32)(row * 64 + (l & 3) * 16)) ^ (((uint32)(row & 7)) << 4);
        *(s8v*)((char*)Ks[hs] + kb) = rk;
    }
    // prefetch all 4 Q fragments (hides global latency outside the chain)
    const int qoff = h * ND + g * 8;
    s8v qf4[4];
    #pragma unroll
    for (int i = 0; i < 4; ++i)
        qf4[i] = *(const s8v*)(base + (size_t)(16 * (4 * th + i) + c) * tokStride + qoff);
    __syncthreads();
    // V^T fragments from LDS: vf[ks][ni][j] = V[32ks+8g+j][16ni+c]
    s8v vf[4][2];
    #pragma unroll
    for (int ks = 0; ks < 4; ++ks)
        #pragma unroll
        for (int ni = 0; ni < 2; ++ni) {
            s8v tmp;
            #pragma unroll
            for (int j = 0; j < 8; ++j)
                tmp[j] = (short)Vs[hs][(32 * ks + 8 * g + j) * ND + 16 * ni + c];
            vf[ks][ni] = tmp;
        }

    ush* og = O + ((size_t)b * NT * NV + v) * NC + h * ND;
    const int ga = (g & 1) * 2;
    const int l1 = ga * 16 + c, l2 = l1 + 16;
    const bool hisel = (g >> 1) != 0;
    const char* KsB = (const char*)Ks[hs];

    #pragma unroll
    for (int i = 0; i < 4; ++i) {
        const int t16 = 4 * th + i;
        const s8v qf = qf4[i];
        f4v st[8];
        #pragma unroll
        for (int si = 0; si < 8; ++si) {
            if (MASKED && si > t16) { st[si] = (f4v){0.f, 0.f, 0.f, 0.f}; continue; }
            const int krow = 16 * si + c;
            const uint32 rb = ((uint32)(krow * 64 + g * 16)) ^ (((uint32)(krow & 7)) << 4);
            s8v kf = *(const s8v*)(KsB + rb);
            st[si] = __builtin_amdgcn_mfma_f32_16x16x32_bf16(kf, qf,
                                                             (f4v){0.f, 0.f, 0.f, 0.f}, 0, 0, 0);
        }
        const int t = 16 * t16 + c;
        if (MASKED) {
            #pragma unroll
            for (int si = 0; si < 8; ++si) {
                if (si > t16) continue;
                #pragma unroll
                for (int r = 0; r < 4; ++r)
                    if (16 * si + 4 * g + r > t) st[si][r] = -1e30f;
            }
        }
        float mx = -1e30f;
        #pragma unroll
        for (int si = 0; si < 8; ++si) {
            if (MASKED && si > t16) continue;
            #pragma unroll
            for (int r = 0; r < 4; ++r) mx = fmaxf(mx, st[si][r]);
        }
        mx = fmaxf(mx, __shfl_xor(mx, 16));
        mx = fmaxf(mx, __shfl_xor(mx, 32));
        float sm = 0.f;
        #pragma unroll
        for (int si = 0; si < 8; ++si) {
            if (MASKED && si > t16) continue;
            #pragma unroll
            for (int r = 0; r < 4; ++r) {
                float e = __expf((st[si][r] - mx) * QSCALE);
                st[si][r] = e;
                sm += e;
            }
        }
        sm += __shfl_xor(sm, 16);
        sm += __shfl_xor(sm, 32);
        const float inv = 1.f / sm;
        uint32 u[8][2];
        #pragma unroll
        for (int si = 0; si < 8; ++si) {
            if (MASKED && si > t16) { u[si][0] = 0u; u[si][1] = 0u; continue; }
            float e0 = st[si][0] * inv, e1 = st[si][1] * inv;
            float e2 = st[si][2] * inv, e3 = st[si][3] * inv;
            asm("v_cvt_pk_bf16_f32 %0, %1, %2" : "=v"(u[si][0]) : "v"(e0), "v"(e1));
            asm("v_cvt_pk_bf16_f32 %0, %1, %2" : "=v"(u[si][1]) : "v"(e2), "v"(e3));
        }
        f4v o[2] = {};
        #pragma unroll
        for (int ks = 0; ks < 4; ++ks) {
            if (MASKED && 2 * ks > t16) continue;
            uint32 w0a = __shfl(u[2 * ks][0], l1),     w0b = __shfl(u[2 * ks][1], l1);
            uint32 w0c = __shfl(u[2 * ks][0], l2),     w0d = __shfl(u[2 * ks][1], l2);
            uint32 w1a = __shfl(u[2 * ks + 1][0], l1), w1b = __shfl(u[2 * ks + 1][1], l1);
            uint32 w1c = __shfl(u[2 * ks + 1][0], l2), w1d = __shfl(u[2 * ks + 1][1], l2);
            union { uint32 w[4]; s8v s; } pa;
            pa.w[0] = hisel ? w1a : w0a;
            pa.w[1] = hisel ? w1b : w0b;
            pa.w[2] = hisel ? w1c : w0c;
            pa.w[3] = hisel ? w1d : w0d;
            o[0] = __builtin_amdgcn_mfma_f32_16x16x32_bf16(pa.s, vf[ks][0], o[0], 0, 0, 0);
            o[1] = __builtin_amdgcn_mfma_f32_16x16x32_bf16(pa.s, vf[ks][1], o[1], 0, 0, 0);
        }
        #pragma unroll
        for (int ni = 0; ni < 2; ++ni)
            #pragma unroll
            for (int r = 0; r < 4; ++r)
                og[(size_t)(16 * t16 + 4 * g + r) * (NV * NC) + 16 * ni + c] = f2bf(o[ni][r]);
    }
}

// ---------------- row LayerNorm (unbiased std), in place, 1 wave = 1 row ----------------
__global__ __launch_bounds__(256) void k_ln(
    ush* __restrict__ buf, const ush* __restrict__ g, const ush* __restrict__ bb)
{
    const int row = blockIdx.x * 4 + (threadIdx.x >> 6);
    const int lane = threadIdx.x & 63;
    ush* p = buf + (size_t)row * NC + lane * 4;
    uint2 u = *(uint2*)p;
    float x0 = bf2f((ush)(u.x & 0xffff)), x1 = bf2f((ush)(u.x >> 16));
    float x2 = bf2f((ush)(u.y & 0xffff)), x3 = bf2f((ush)(u.y >> 16));
    float s = x0 + x1 + x2 + x3;
    float q = x0 * x0 + x1 * x1 + x2 * x2 + x3 * x3;
    #pragma unroll
    for (int o = 32; o; o >>= 1) { s += __shfl_xor(s, o); q += __shfl_xor(q, o); }
    float mean = s * (1.f / 256.f);
    float var = fmaxf((q - 256.f * mean * mean) * (1.f / 255.f), 0.f);
    float inv = 1.f / (sqrtf(var) + LN_EPS);
    float o0 = bf2f(g[lane * 4 + 0]) * (x0 - mean) * inv + bf2f(bb[lane * 4 + 0]);
    float o1 = bf2f(g[lane * 4 + 1]) * (x1 - mean) * inv + bf2f(bb[lane * 4 + 1]);
    float o2 = bf2f(g[lane * 4 + 2]) * (x2 - mean) * inv + bf2f(bb[lane * 4 + 2]);
    float o3 = bf2f(g[lane * 4 + 3]) * (x3 - mean) * inv + bf2f(bb[lane * 4 + 3]);
    uint32 lo = pack2(o0, o1);
    uint32 hi = pack2(o2, o3);
    *(uint2*)p = make_uint2(lo, hi);
}

// -------- GCN via MFMA: per (b,t): h3[32 w][256 c] = A2[32][96] @ X[96][256] --------
__global__ __launch_bounds__(256) void k_gcn_mfma(
    const ush* __restrict__ xw, const ush* __restrict__ A2,
    const float* __restrict__ cs4,
    const ush* __restrict__ bg, const ush* __restrict__ g3, const ush* __restrict__ b3,
    float* __restrict__ outp)
{
    const int t = blockIdx.x, b = blockIdx.y;
    const int tid = threadIdx.x;
    __shared__ uint4 Xs4[2400];                 // 38.4KB: X tile, swizzled
    char* Xs = (char*)Xs4;
    float* h3s = (float*)Xs4;                   // [25][260] f32 overlay after barrier
    const int l = tid & 63, wv = tid >> 6, g = l >> 4, c4 = l & 15;

    s8v af[2][3];
    #pragma unroll
    for (int mi = 0; mi < 2; ++mi)
        #pragma unroll
        for (int ks = 0; ks < 3; ++ks)
            af[mi][ks] = *(const s8v*)&A2[(mi * 16 + c4) * 96 + ks * 32 + g * 8];

    const ush* xr = xw + ((size_t)(b * NT + t)) * NV * NKC;
    for (int i = tid; i < 2400; i += 256) {
        int v = i / 96, c8 = i - v * 96;
        uint32 off = (uint32)(v * 1536 + c8 * 16) ^ (((v >> 3) & 3) << 4);
        *(uint4*)(Xs + off) = *(const uint4*)&xr[(size_t)v * NKC + c8 * 8];
    }
    __syncthreads();

    f4v acc[2][4] = {};
    const int c0 = wv * 64;
    #pragma unroll
    for (int ks = 0; ks < 3; ++ks) {
        #pragma unroll
        for (int ni = 0; ni < 4; ++ni) {
            const int c = c0 + ni * 16 + c4;
            s8v bfr;
            #pragma unroll
            for (int j = 0; j < 8; ++j) {
                int v = g * 8 + j; if (v > 24) v = 24;
                uint32 off = (uint32)(v * 1536 + ks * 512 + c * 2) ^ (((v >> 3) & 3) << 4);
                bfr[j] = *(const short*)(Xs + off);
            }
            acc[0][ni] = __builtin_amdgcn_mfma_f32_16x16x32_bf16(af[0][ks], bfr, acc[0][ni], 0, 0, 0);
            acc[1][ni] = __builtin_amdgcn_mfma_f32_16x16x32_bf16(af[1][ks], bfr, acc[1][ni], 0, 0, 0);
        }
    }
    __syncthreads();
    #pragma unroll
    for (int mi = 0; mi < 2; ++mi)
        #pragma unroll
        for (int r = 0; r < 4; ++r) {
            const int w = mi * 16 + g * 4 + r;
            if (w < NV) {
                #pragma unroll
                for (int ni = 0; ni < 4; ++ni)
                    h3s[w * 260 + c0 + ni * 16 + c4] = acc[mi][ni][r];
            }
        }
    __syncthreads();
    {
        const int lane = tid & 63;
        float bgq[3][4];
        #pragma unroll
        for (int k = 0; k < 3; ++k)
            #pragma unroll
            for (int i = 0; i < 4; ++i)
                bgq[k][i] = bf2f(bg[k * NC + lane * 4 + i]);
        for (int w = wv; w < NV; w += 4) {
            float4 xq = *(const float4*)&h3s[w * 260 + lane * 4];
            const float cw0 = cs4[w * 4], cw1 = cs4[w * 4 + 1], cw2 = cs4[w * 4 + 2];
            xq.x += cw0 * bgq[0][0] + cw1 * bgq[1][0] + cw2 * bgq[2][0];
            xq.y += cw0 * bgq[0][1] + cw1 * bgq[1][1] + cw2 * bgq[2][1];
            xq.z += cw0 * bgq[0][2] + cw1 * bgq[1][2] + cw2 * bgq[2][2];
            xq.w += cw0 * bgq[0][3] + cw1 * bgq[1][3] + cw2 * bgq[2][3];
            float s = xq.x + xq.y + xq.z + xq.w;
            float q = xq.x * xq.x + xq.y * xq.y + xq.z * xq.z + xq.w * xq.w;
            #pragma unroll
            for (int o = 32; o; o >>= 1) { s += __shfl_xor(s, o); q += __shfl_xor(q, o); }
            float mean = s * (1.f / 256.f);
            float var = fmaxf((q - 256.f * mean * mean) * (1.f / 255.f), 0.f);
            float inv = 1.f / (sqrtf(var) + LN_EPS);
            float o0 = bf2f(g3[lane * 4 + 0]) * (xq.x - mean) * inv + bf2f(b3[lane * 4 + 0]);
            float o1 = bf2f(g3[lane * 4 + 1]) * (xq.y - mean) * inv + bf2f(b3[lane * 4 + 1]);
            float o2 = bf2f(g3[lane * 4 + 2]) * (xq.z - mean) * inv + bf2f(b3[lane * 4 + 2]);
            float o3 = bf2f(g3[lane * 4 + 3]) * (xq.w - mean) * inv + bf2f(b3[lane * 4 + 3]);
            float* op = outp + (((size_t)(b * NT + t)) * NV + w) * NC + lane * 4;
            *(float4*)op = make_float4(o0, o1, o2, o3);
        }
    }
}

extern "C" void kernel_launch(void* const* d_in, const int* in_sizes, int n_in,
                              void* d_out, int out_size, void* d_ws, size_t ws_size,
                              hipStream_t stream)
{
    const size_t NTOK = (size_t)NB * NT * NV;   // 51200
    char* ws = (char*)d_ws;
    int* flag = (int*)ws;
    ush* A2 = (ush*)(ws + 256);                 // [32][96] bf16, 6KB
    float* cs4 = (float*)(ws + 256 + 6144);     // [25][4] f32, 400B
    ush* bufA = (ush*)(ws + 16384);             // [M,768]  78.6MB
    ush* bufB = bufA + NTOK * NKC;              // [M,256]  26.2MB
    ush* conv = bufB + NTOK * NC;

    k_detect<<<1, 256, 0, stream>>>((const uint32*)d_in[0], flag);
    k_convA<<<1, 256, 0, stream>>>(d_in[2], A2, cs4, flag);

    // ---- one-launch conversion table ----
    CvTab tab;
    int nent = 0, blk = 0;
    ush* p = conv;
    const ush* cp[18] = {};
    auto add = [&](int idx, int n, int K, int N, ush*& dst_out) {
        tab.e[nent] = { d_in[idx], p, n, K, N, blk };
        dst_out = p;
        blk += (K == 0) ? (n + 2047) / 2048 : (n + 1023) / 1024;
        p += (size_t)((n + 7) & ~7);
        ++nent;
    };
    ush* d;
    add(0, NB * NT * NV * NCIN, 0, 0, d);  cp[0] = d;
    add(1, NB * NTM * NV * NCM, 0, 0, d);  cp[1] = d;
    add(15, NKC, 0, 0, d);                 cp[15] = d;
    add(7, NC, 0, 0, d);  cp[7] = d;
    add(8, NC, 0, 0, d);  cp[8] = d;
    add(12, NC, 0, 0, d); cp[12] = d;
    add(13, NC, 0, 0, d); cp[13] = d;
    add(16, NC, 0, 0, d); cp[16] = d;
    add(17, NC, 0, 0, d); cp[17] = d;
    ush* w1t;
    add(4, NCIN * NC, NCIN, NC, w1t);      // [256][64] q
    add(5, NCIN * NC, NCIN, NC, d);        // k  (contiguous after q)
    add(6, NCIN * NC, NCIN, NC, d);        // v
    ush* wq2t;
    add(9, NC * NC, NC, NC, wq2t);         // [256][256]
    ush* wkv2t;
    add(10, NCM * NC, NCM, NC, wkv2t);     // [256][256] k
    add(11, NCM * NC, NCM, NC, d);         // v (contiguous)
    ush* wgt;
    add(14, NC * NKC, NC, NKC, wgt);       // [768][256]
    k_convall<<<blk, 256, 0, stream>>>(tab, flag);

    const int M = (int)NTOK;
    // stage 1: qkv1 = x @ [Wq1|Wk1|Wv1]  -> bufA [M,768]
    k_gemm<<<dim3(6, M / 128), 256, 0, stream>>>(cp[0], w1t, bufA, M, NCIN, NKC);
    k_attn_mfma<1><<<dim3(NV, NH / 4, NB), 512, 0, stream>>>(bufA, bufB);
    k_ln<<<M / 4, 256, 0, stream>>>(bufB, cp[7], cp[8]);
    // stage 2 (one launch): q2 = h1@Wq2 (cols 0-255) + kv2 = m@[Wk2|Wv2] (cols 256-767)
    k_gemm_s2<<<dim3(6, M / 128), 256, 0, stream>>>(bufB, cp[1], wq2t, wkv2t, bufA, M);
    k_attn_mfma<0><<<dim3(NV, NH / 4, NB), 512, 0, stream>>>(bufA, bufB);
    k_ln<<<M / 4, 256, 0, stream>>>(bufB, cp[12], cp[13]);
    // stage 3: xw = h2 @ Wg -> bufA [M,768]; then MFMA GCN + LN -> out
    k_gemm<<<dim3(6, M / 128), 256, 0, stream>>>(bufB, wgt, bufA, M, NC, NKC);
    k_gcn_mfma<<<dim3(NT, NB), 256, 0, stream>>>(bufA, A2, cs4, cp[15], cp[16], cp[17],
                                                 (float*)d_out);
}

// Round 20
// 233.255 us; speedup vs baseline: 1.0714x; 1.0526x over previous
//
#include <hip/hip_runtime.h>
#include <hip/hip_bf16.h>

typedef unsigned short ush;
typedef unsigned int uint32;
typedef __attribute__((ext_vector_type(8))) short s8v;   // 8 bf16 (4 VGPRs)
typedef __attribute__((ext_vector_type(4))) float f4v;   // MFMA accumulator

#define NB 16
#define NT 128
#define NTM 128
#define NV 25
#define NCIN 64
#define NCM 256
#define NH 8
#define ND 32
#define NC 256
#define NK 3
#define NKC 768
#define LN_EPS 1e-6f
#define QSCALE 0.17677669529663687f

__device__ __forceinline__ float bf2f(ush u) {
    union { uint32 i; float f; } x; x.i = ((uint32)u) << 16; return x.f;
}
__device__ __forceinline__ ush f2bf(float f) {
    union { float f; uint32 i; } x; x.f = f;
    uint32 r = x.i + 0x7FFFu + ((x.i >> 16) & 1u);
    return (ush)(r >> 16);
}
__device__ __forceinline__ uint32 pack2(float a, float b) {
    return (uint32)f2bf(a) | ((uint32)f2bf(b) << 16);
}

// -------- dtype detector (f32 vs bf16 device buffers) --------
__global__ __launch_bounds__(256) void k_detect(const uint32* __restrict__ xw,
                                               int* __restrict__ flag)
{
    __shared__ int cnt;
    if (threadIdx.x == 0) cnt = 0;
    __syncthreads();
    int c = 0;
    for (int i = 0; i < 4; ++i) {
        uint32 u = xw[threadIdx.x + 256 * i];
        uint32 e = (u >> 7) & 0xFF;
        c += (e >= 100 && e <= 135) ? 1 : 0;
    }
    atomicAdd(&cnt, c);
    __syncthreads();
    if (threadIdx.x == 0) *flag = (cnt > 700) ? 1 : 0;   // 1 = bf16, 0 = f32
}

// A [k][v][w] -> A2 bf16 [32 w][96 kk], kk = k*32+v (pad w>=25, v>=25 with 0)
//             + cs4[w][4]: cs4[w*4+k] = sum_v A[k][v][w]
__global__ __launch_bounds__(256) void k_convA(const void* __restrict__ src,
                                               ush* __restrict__ A2,
                                               float* __restrict__ cs4,
                                               const int* __restrict__ flag)
{
    const bool isbf = (*flag != 0);
    const int tid = threadIdx.x;
    __shared__ float As[1875];
    for (int i = tid; i < 1875; i += 256)
        As[i] = isbf ? bf2f(((const ush*)src)[i]) : ((const float*)src)[i];
    __syncthreads();
    for (int j = tid; j < 32 * 96; j += 256) {
        int w = j / 96, kk = j - w * 96, k = kk >> 5, v = kk & 31;
        float val = (w < NV && v < NV) ? As[k * 625 + v * 25 + w] : 0.f;
        A2[j] = f2bf(val);
    }
    for (int j = tid; j < 100; j += 256) {
        int w = j >> 2, k = j & 3;
        float s = 0.f;
        if (k < 3)
            for (int v = 0; v < NV; ++v) s += As[k * 625 + v * 25 + w];
        cs4[j] = s;
    }
}

// -------- single-launch converter --------
struct CvEnt { const void* src; ush* dst; int n; int K; int N; int blk0; };
struct CvTab { CvEnt e[16]; };

__global__ __launch_bounds__(256) void k_convall(CvTab tab, const int* __restrict__ flag)
{
    const bool isbf = (*flag != 0);
    const int bi = (int)blockIdx.x;
    int ei = 0;
    #pragma unroll
    for (int i = 1; i < 16; ++i) if (bi >= tab.e[i].blk0) ei = i;
    const CvEnt& e = tab.e[ei];
    if (e.K == 0) {
        const int idx = (bi - e.blk0) * 2048 + (int)threadIdx.x * 8;
        if (idx >= e.n) return;
        if (isbf) {
            *(uint4*)&e.dst[idx] = *(const uint4*)((const ush*)e.src + idx);
        } else {
            const float* s = (const float*)e.src + idx;
            uint4 a = *(const uint4*)s;
            uint4 b = *(const uint4*)(s + 4);
            uint4 o;
            o.x = pack2(((float*)&a)[0], ((float*)&a)[1]);
            o.y = pack2(((float*)&a)[2], ((float*)&a)[3]);
            o.z = pack2(((float*)&b)[0], ((float*)&b)[1]);
            o.w = pack2(((float*)&b)[2], ((float*)&b)[3]);
            *(uint4*)&e.dst[idx] = o;
        }
    } else {
        const int s4 = (bi - e.blk0) * 1024 + (int)threadIdx.x * 4;
        if (s4 >= e.n) return;
        const int k = s4 / e.N, n0 = s4 - k * e.N;
        float v0, v1, v2, v3;
        if (isbf) {
            const ush* s = (const ush*)e.src + s4;
            v0 = bf2f(s[0]); v1 = bf2f(s[1]); v2 = bf2f(s[2]); v3 = bf2f(s[3]);
        } else {
            float4 f = *(const float4*)((const float*)e.src + s4);
            v0 = f.x; v1 = f.y; v2 = f.z; v3 = f.w;
        }
        ush* d = e.dst + (size_t)n0 * e.K + k;
        d[0] = f2bf(v0);
        d[e.K] = f2bf(v1);
        d[2 * e.K] = f2bf(v2);
        d[3 * e.K] = f2bf(v3);
    }
}

// XCD-aware bijective swizzle of the linear block index (requires nwg % 8 == 0)
__device__ __forceinline__ void xcd_swz(int& bx, int& by) {
    const int gx = gridDim.x, nwg = gx * gridDim.y;
    int lin = by * gx + bx;
    lin = (lin & 7) * (nwg >> 3) + (lin >> 3);
    bx = lin % gx;
    by = lin / gx;
}

// -------- MFMA GEMM: C[M, cols n0..] = A[M,K] @ Bt[N,K]^T --------
__global__ __launch_bounds__(256) void k_gemm(
    const ush* __restrict__ A, const ush* __restrict__ Bt, ush* __restrict__ C,
    int M, int K, int ldC)
{
    int bx = blockIdx.x, by = blockIdx.y;
    xcd_swz(bx, by);
    const int n0 = bx * 128, m0 = by * 128;
    const int tid = threadIdx.x, w = tid >> 6, l = tid & 63;
    __shared__ ush As[8192], Bs[8192];
    const char* AsB = (const char*)As;
    const char* BsB = (const char*)Bs;
    const int rl = l >> 3, cc = l & 7;
    f4v acc[4][4] = {};
    const int wm = w >> 1, wn = w & 1;

    for (int kt = 0; kt < K; kt += 64) {
        __syncthreads();
        #pragma unroll
        for (int j = 0; j < 4; ++j) {
            const int r = (w * 4 + j) * 8 + rl;
            const int sc = (cc ^ (r & 7)) * 8;
            const ush* ga = &A[(size_t)(m0 + r) * K + kt + sc];
            const ush* gb = &Bt[(size_t)(n0 + r) * K + kt + sc];
            __builtin_amdgcn_global_load_lds(
                (const __attribute__((address_space(1))) uint32*)ga,
                (__attribute__((address_space(3))) uint32*)&As[(w * 4 + j) * 512], 16, 0, 0);
            __builtin_amdgcn_global_load_lds(
                (const __attribute__((address_space(1))) uint32*)gb,
                (__attribute__((address_space(3))) uint32*)&Bs[(w * 4 + j) * 512], 16, 0, 0);
        }
        __syncthreads();
        #pragma unroll
        for (int ks = 0; ks < 2; ++ks) {
            const int ko = ks * 64 + (l >> 4) * 16;
            s8v a[4], b[4];
            #pragma unroll
            for (int mi = 0; mi < 4; ++mi) {
                const int ra = wm * 64 + mi * 16 + (l & 15);
                a[mi] = *(const s8v*)(AsB + ra * 128 + (ko ^ ((ra & 7) << 4)));
            }
            #pragma unroll
            for (int ni = 0; ni < 4; ++ni) {
                const int rb = wn * 64 + ni * 16 + (l & 15);
                b[ni] = *(const s8v*)(BsB + rb * 128 + (ko ^ ((rb & 7) << 4)));
            }
            #pragma unroll
            for (int mi = 0; mi < 4; ++mi)
                #pragma unroll
                for (int ni = 0; ni < 4; ++ni)
                    acc[mi][ni] = __builtin_amdgcn_mfma_f32_16x16x32_bf16(a[mi], b[ni],
                                                                          acc[mi][ni], 0, 0, 0);
        }
    }
    const int col = n0 + wn * 64 + (l & 15);
    #pragma unroll
    for (int mi = 0; mi < 4; ++mi) {
        const int row_base = m0 + wm * 64 + mi * 16 + (l >> 4) * 4;
        #pragma unroll
        for (int ni = 0; ni < 4; ++ni)
            #pragma unroll
            for (int r = 0; r < 4; ++r)
                C[(size_t)(row_base + r) * ldC + col + ni * 16] = f2bf(acc[mi][ni][r]);
    }
}

// -------- merged stage-2 GEMM: bx<2 -> q2 = h1@Wq2 ; bx>=2 -> kv2 = m@Wkv2 --------
__global__ __launch_bounds__(256) void k_gemm_s2(
    const ush* __restrict__ Aq, const ush* __restrict__ Akv,
    const ush* __restrict__ Btq, const ush* __restrict__ Btkv,
    ush* __restrict__ C, int M)
{
    int bx = blockIdx.x, by = blockIdx.y;
    xcd_swz(bx, by);
    const ush* A = (bx < 2) ? Aq : Akv;
    const ush* Bt = (bx < 2) ? (Btq + (size_t)(bx * 128) * NC)
                             : (Btkv + (size_t)((bx - 2) * 128) * NC);
    const int c0 = bx * 128, m0 = by * 128;
    const int K = NC, ldC = NKC;
    const int tid = threadIdx.x, w = tid >> 6, l = tid & 63;
    __shared__ ush As[8192], Bs[8192];
    const char* AsB = (const char*)As;
    const char* BsB = (const char*)Bs;
    const int rl = l >> 3, cc = l & 7;
    f4v acc[4][4] = {};
    const int wm = w >> 1, wn = w & 1;

    for (int kt = 0; kt < K; kt += 64) {
        __syncthreads();
        #pragma unroll
        for (int j = 0; j < 4; ++j) {
            const int r = (w * 4 + j) * 8 + rl;
            const int sc = (cc ^ (r & 7)) * 8;
            const ush* ga = &A[(size_t)(m0 + r) * K + kt + sc];
            const ush* gb = &Bt[(size_t)r * K + kt + sc];
            __builtin_amdgcn_global_load_lds(
                (const __attribute__((address_space(1))) uint32*)ga,
                (__attribute__((address_space(3))) uint32*)&As[(w * 4 + j) * 512], 16, 0, 0);
            __builtin_amdgcn_global_load_lds(
                (const __attribute__((address_space(1))) uint32*)gb,
                (__attribute__((address_space(3))) uint32*)&Bs[(w * 4 + j) * 512], 16, 0, 0);
        }
        __syncthreads();
        #pragma unroll
        for (int ks = 0; ks < 2; ++ks) {
            const int ko = ks * 64 + (l >> 4) * 16;
            s8v a[4], b[4];
            #pragma unroll
            for (int mi = 0; mi < 4; ++mi) {
                const int ra = wm * 64 + mi * 16 + (l & 15);
                a[mi] = *(const s8v*)(AsB + ra * 128 + (ko ^ ((ra & 7) << 4)));
            }
            #pragma unroll
            for (int ni = 0; ni < 4; ++ni) {
                const int rb = wn * 64 + ni * 16 + (l & 15);
                b[ni] = *(const s8v*)(BsB + rb * 128 + (ko ^ ((rb & 7) << 4)));
            }
            #pragma unroll
            for (int mi = 0; mi < 4; ++mi)
                #pragma unroll
                for (int ni = 0; ni < 4; ++ni)
                    acc[mi][ni] = __builtin_amdgcn_mfma_f32_16x16x32_bf16(a[mi], b[ni],
                                                                          acc[mi][ni], 0, 0, 0);
        }
    }
    const int col = c0 + wn * 64 + (l & 15);
    #pragma unroll
    for (int mi = 0; mi < 4; ++mi) {
        const int row_base = m0 + wm * 64 + mi * 16 + (l >> 4) * 4;
        #pragma unroll
        for (int ni = 0; ni < 4; ++ni)
            #pragma unroll
            for (int r = 0; r < 4; ++r)
                C[(size_t)(row_base + r) * ldC + col + ni * 16] = f2bf(acc[mi][ni][r]);
    }
}

// -------- MFMA attention: 8 waves = 4 heads x 2 t-halves; K AND V in LDS --------
// (r17 configuration: compiler-chosen VGPR budget, qf loaded in-loop)
template<int MASKED>
__global__ __launch_bounds__(512) void k_attn_mfma(
    const ush* __restrict__ QKV, ush* __restrict__ O)
{
    const int v = blockIdx.x, hq = blockIdx.y, b = blockIdx.z;
    const int tid = threadIdx.x, wv = tid >> 6, l = tid & 63;
    const int hs = wv >> 1, th = wv & 1;
    const int h = hq * 4 + hs;
    const int g = l >> 4, c = l & 15;
    __shared__ ush Vs[4][NT * ND];   // 32 KB linear V
    __shared__ ush Ks[4][NT * ND];   // 32 KB swizzled K
    const size_t tokStride = (size_t)NV * NKC;
    const ush* base = QKV + ((size_t)b * NT * NV + v) * NKC;

    const int vrow = l >> 2, vch = (l & 3) * 8;
    #pragma unroll
    for (int i = 0; i < 4; ++i) {
        const int row = 16 * (4 * th + i) + vrow;
        s8v rv = *(const s8v*)(base + (size_t)row * tokStride + 512 + h * ND + vch);
        *(s8v*)&Vs[hs][row * ND + vch] = rv;
        s8v rk = *(const s8v*)(base + (size_t)row * tokStride + 256 + h * ND + vch);
        const uint32 kb = ((uint32)(row * 64 + (l & 3) * 16)) ^ (((uint32)(row & 7)) << 4);
        *(s8v*)((char*)Ks[hs] + kb) = rk;
    }
    __syncthreads();
    // V^T fragments from LDS: vf[ks][ni][j] = V[32ks+8g+j][16ni+c]
    s8v vf[4][2];
    #pragma unroll
    for (int ks = 0; ks < 4; ++ks)
        #pragma unroll
        for (int ni = 0; ni < 2; ++ni) {
            s8v tmp;
            #pragma unroll
            for (int j = 0; j < 8; ++j)
                tmp[j] = (short)Vs[hs][(32 * ks + 8 * g + j) * ND + 16 * ni + c];
            vf[ks][ni] = tmp;
        }

    ush* og = O + ((size_t)b * NT * NV + v) * NC + h * ND;
    const int qoff = h * ND + g * 8;
    const int ga = (g & 1) * 2;
    const int l1 = ga * 16 + c, l2 = l1 + 16;
    const bool hisel = (g >> 1) != 0;
    const char* KsB = (const char*)Ks[hs];

    for (int i = 0; i < 4; ++i) {
        const int t16 = 4 * th + i;
        s8v qf = *(const s8v*)(base + (size_t)(16 * t16 + c) * tokStride + qoff);
        f4v st[8];
        #pragma unroll
        for (int si = 0; si < 8; ++si) {
            if (MASKED && si > t16) { st[si] = (f4v){0.f, 0.f, 0.f, 0.f}; continue; }
            const int krow = 16 * si + c;
            const uint32 rb = ((uint32)(krow * 64 + g * 16)) ^ (((uint32)(krow & 7)) << 4);
            s8v kf = *(const s8v*)(KsB + rb);
            st[si] = __builtin_amdgcn_mfma_f32_16x16x32_bf16(kf, qf,
                                                             (f4v){0.f, 0.f, 0.f, 0.f}, 0, 0, 0);
        }
        const int t = 16 * t16 + c;
        if (MASKED) {
            #pragma unroll
            for (int si = 0; si < 8; ++si) {
                if (si > t16) continue;
                #pragma unroll
                for (int r = 0; r < 4; ++r)
                    if (16 * si + 4 * g + r > t) st[si][r] = -1e30f;
            }
        }
        float mx = -1e30f;
        #pragma unroll
        for (int si = 0; si < 8; ++si) {
            if (MASKED && si > t16) continue;
            #pragma unroll
            for (int r = 0; r < 4; ++r) mx = fmaxf(mx, st[si][r]);
        }
        mx = fmaxf(mx, __shfl_xor(mx, 16));
        mx = fmaxf(mx, __shfl_xor(mx, 32));
        float sm = 0.f;
        #pragma unroll
        for (int si = 0; si < 8; ++si) {
            if (MASKED && si > t16) continue;
            #pragma unroll
            for (int r = 0; r < 4; ++r) {
                float e = __expf((st[si][r] - mx) * QSCALE);
                st[si][r] = e;
                sm += e;
            }
        }
        sm += __shfl_xor(sm, 16);
        sm += __shfl_xor(sm, 32);
        const float inv = 1.f / sm;
        uint32 u[8][2];
        #pragma unroll
        for (int si = 0; si < 8; ++si) {
            if (MASKED && si > t16) { u[si][0] = 0u; u[si][1] = 0u; continue; }
            float e0 = st[si][0] * inv, e1 = st[si][1] * inv;
            float e2 = st[si][2] * inv, e3 = st[si][3] * inv;
            asm("v_cvt_pk_bf16_f32 %0, %1, %2" : "=v"(u[si][0]) : "v"(e0), "v"(e1));
            asm("v_cvt_pk_bf16_f32 %0, %1, %2" : "=v"(u[si][1]) : "v"(e2), "v"(e3));
        }
        f4v o[2] = {};
        #pragma unroll
        for (int ks = 0; ks < 4; ++ks) {
            if (MASKED && 2 * ks > t16) continue;
            uint32 w0a = __shfl(u[2 * ks][0], l1),     w0b = __shfl(u[2 * ks][1], l1);
            uint32 w0c = __shfl(u[2 * ks][0], l2),     w0d = __shfl(u[2 * ks][1], l2);
            uint32 w1a = __shfl(u[2 * ks + 1][0], l1), w1b = __shfl(u[2 * ks + 1][1], l1);
            uint32 w1c = __shfl(u[2 * ks + 1][0], l2), w1d = __shfl(u[2 * ks + 1][1], l2);
            union { uint32 w[4]; s8v s; } pa;
            pa.w[0] = hisel ? w1a : w0a;
            pa.w[1] = hisel ? w1b : w0b;
            pa.w[2] = hisel ? w1c : w0c;
            pa.w[3] = hisel ? w1d : w0d;
            o[0] = __builtin_amdgcn_mfma_f32_16x16x32_bf16(pa.s, vf[ks][0], o[0], 0, 0, 0);
            o[1] = __builtin_amdgcn_mfma_f32_16x16x32_bf16(pa.s, vf[ks][1], o[1], 0, 0, 0);
        }
        #pragma unroll
        for (int ni = 0; ni < 2; ++ni)
            #pragma unroll
            for (int r = 0; r < 4; ++r)
                og[(size_t)(16 * t16 + 4 * g + r) * (NV * NC) + 16 * ni + c] = f2bf(o[ni][r]);
    }
}

// ---------------- row LayerNorm (unbiased std), in place, 1 wave = 1 row ----------------
__global__ __launch_bounds__(256) void k_ln(
    ush* __restrict__ buf, const ush* __restrict__ g, const ush* __restrict__ bb)
{
    const int row = blockIdx.x * 4 + (threadIdx.x >> 6);
    const int lane = threadIdx.x & 63;
    ush* p = buf + (size_t)row * NC + lane * 4;
    uint2 u = *(uint2*)p;
    float x0 = bf2f((ush)(u.x & 0xffff)), x1 = bf2f((ush)(u.x >> 16));
    float x2 = bf2f((ush)(u.y & 0xffff)), x3 = bf2f((ush)(u.y >> 16));
    float s = x0 + x1 + x2 + x3;
    float q = x0 * x0 + x1 * x1 + x2 * x2 + x3 * x3;
    #pragma unroll
    for (int o = 32; o; o >>= 1) { s += __shfl_xor(s, o); q += __shfl_xor(q, o); }
    float mean = s * (1.f / 256.f);
    float var = fmaxf((q - 256.f * mean * mean) * (1.f / 255.f), 0.f);
    float inv = 1.f / (sqrtf(var) + LN_EPS);
    float o0 = bf2f(g[lane * 4 + 0]) * (x0 - mean) * inv + bf2f(bb[lane * 4 + 0]);
    float o1 = bf2f(g[lane * 4 + 1]) * (x1 - mean) * inv + bf2f(bb[lane * 4 + 1]);
    float o2 = bf2f(g[lane * 4 + 2]) * (x2 - mean) * inv + bf2f(bb[lane * 4 + 2]);
    float o3 = bf2f(g[lane * 4 + 3]) * (x3 - mean) * inv + bf2f(bb[lane * 4 + 3]);
    uint32 lo = pack2(o0, o1);
    uint32 hi = pack2(o2, o3);
    *(uint2*)p = make_uint2(lo, hi);
}

// -------- GCN via MFMA: per (b,t): h3[32 w][256 c] = A2[32][96] @ X[96][256] --------
__global__ __launch_bounds__(256) void k_gcn_mfma(
    const ush* __restrict__ xw, const ush* __restrict__ A2,
    const float* __restrict__ cs4,
    const ush* __restrict__ bg, const ush* __restrict__ g3, const ush* __restrict__ b3,
    float* __restrict__ outp)
{
    const int t = blockIdx.x, b = blockIdx.y;
    const int tid = threadIdx.x;
    __shared__ uint4 Xs4[2400];                 // 38.4KB: X tile, swizzled
    char* Xs = (char*)Xs4;
    float* h3s = (float*)Xs4;                   // [25][260] f32 overlay after barrier
    const int l = tid & 63, wv = tid >> 6, g = l >> 4, c4 = l & 15;

    s8v af[2][3];
    #pragma unroll
    for (int mi = 0; mi < 2; ++mi)
        #pragma unroll
        for (int ks = 0; ks < 3; ++ks)
            af[mi][ks] = *(const s8v*)&A2[(mi * 16 + c4) * 96 + ks * 32 + g * 8];

    const ush* xr = xw + ((size_t)(b * NT + t)) * NV * NKC;
    for (int i = tid; i < 2400; i += 256) {
        int v = i / 96, c8 = i - v * 96;
        uint32 off = (uint32)(v * 1536 + c8 * 16) ^ (((v >> 3) & 3) << 4);
        *(uint4*)(Xs + off) = *(const uint4*)&xr[(size_t)v * NKC + c8 * 8];
    }
    __syncthreads();

    f4v acc[2][4] = {};
    const int c0 = wv * 64;
    #pragma unroll
    for (int ks = 0; ks < 3; ++ks) {
        #pragma unroll
        for (int ni = 0; ni < 4; ++ni) {
            const int c = c0 + ni * 16 + c4;
            s8v bfr;
            #pragma unroll
            for (int j = 0; j < 8; ++j) {
                int v = g * 8 + j; if (v > 24) v = 24;
                uint32 off = (uint32)(v * 1536 + ks * 512 + c * 2) ^ (((v >> 3) & 3) << 4);
                bfr[j] = *(const short*)(Xs + off);
            }
            acc[0][ni] = __builtin_amdgcn_mfma_f32_16x16x32_bf16(af[0][ks], bfr, acc[0][ni], 0, 0, 0);
            acc[1][ni] = __builtin_amdgcn_mfma_f32_16x16x32_bf16(af[1][ks], bfr, acc[1][ni], 0, 0, 0);
        }
    }
    __syncthreads();
    #pragma unroll
    for (int mi = 0; mi < 2; ++mi)
        #pragma unroll
        for (int r = 0; r < 4; ++r) {
            const int w = mi * 16 + g * 4 + r;
            if (w < NV) {
                #pragma unroll
                for (int ni = 0; ni < 4; ++ni)
                    h3s[w * 260 + c0 + ni * 16 + c4] = acc[mi][ni][r];
            }
        }
    __syncthreads();
    {
        const int lane = tid & 63;
        float bgq[3][4];
        #pragma unroll
        for (int k = 0; k < 3; ++k)
            #pragma unroll
            for (int i = 0; i < 4; ++i)
                bgq[k][i] = bf2f(bg[k * NC + lane * 4 + i]);
        for (int w = wv; w < NV; w += 4) {
            float4 xq = *(const float4*)&h3s[w * 260 + lane * 4];
            const float cw0 = cs4[w * 4], cw1 = cs4[w * 4 + 1], cw2 = cs4[w * 4 + 2];
            xq.x += cw0 * bgq[0][0] + cw1 * bgq[1][0] + cw2 * bgq[2][0];
            xq.y += cw0 * bgq[0][1] + cw1 * bgq[1][1] + cw2 * bgq[2][1];
            xq.z += cw0 * bgq[0][2] + cw1 * bgq[1][2] + cw2 * bgq[2][2];
            xq.w += cw0 * bgq[0][3] + cw1 * bgq[1][3] + cw2 * bgq[2][3];
            float s = xq.x + xq.y + xq.z + xq.w;
            float q = xq.x * xq.x + xq.y * xq.y + xq.z * xq.z + xq.w * xq.w;
            #pragma unroll
            for (int o = 32; o; o >>= 1) { s += __shfl_xor(s, o); q += __shfl_xor(q, o); }
            float mean = s * (1.f / 256.f);
            float var = fmaxf((q - 256.f * mean * mean) * (1.f / 255.f), 0.f);
            float inv = 1.f / (sqrtf(var) + LN_EPS);
            float o0 = bf2f(g3[lane * 4 + 0]) * (xq.x - mean) * inv + bf2f(b3[lane * 4 + 0]);
            float o1 = bf2f(g3[lane * 4 + 1]) * (xq.y - mean) * inv + bf2f(b3[lane * 4 + 1]);
            float o2 = bf2f(g3[lane * 4 + 2]) * (xq.z - mean) * inv + bf2f(b3[lane * 4 + 2]);
            float o3 = bf2f(g3[lane * 4 + 3]) * (xq.w - mean) * inv + bf2f(b3[lane * 4 + 3]);
            float* op = outp + (((size_t)(b * NT + t)) * NV + w) * NC + lane * 4;
            *(float4*)op = make_float4(o0, o1, o2, o3);
        }
    }
}

extern "C" void kernel_launch(void* const* d_in, const int* in_sizes, int n_in,
                              void* d_out, int out_size, void* d_ws, size_t ws_size,
                              hipStream_t stream)
{
    const size_t NTOK = (size_t)NB * NT * NV;   // 51200
    char* ws = (char*)d_ws;
    int* flag = (int*)ws;
    ush* A2 = (ush*)(ws + 256);                 // [32][96] bf16, 6KB
    float* cs4 = (float*)(ws + 256 + 6144);     // [25][4] f32, 400B
    ush* bufA = (ush*)(ws + 16384);             // [M,768]  78.6MB
    ush* bufB = bufA + NTOK * NKC;              // [M,256]  26.2MB
    ush* conv = bufB + NTOK * NC;

    k_detect<<<1, 256, 0, stream>>>((const uint32*)d_in[0], flag);
    k_convA<<<1, 256, 0, stream>>>(d_in[2], A2, cs4, flag);

    // ---- one-launch conversion table ----
    CvTab tab;
    int nent = 0, blk = 0;
    ush* p = conv;
    const ush* cp[18] = {};
    auto add = [&](int idx, int n, int K, int N, ush*& dst_out) {
        tab.e[nent] = { d_in[idx], p, n, K, N, blk };
        dst_out = p;
        blk += (K == 0) ? (n + 2047) / 2048 : (n + 1023) / 1024;
        p += (size_t)((n + 7) & ~7);
        ++nent;
    };
    ush* d;
    add(0, NB * NT * NV * NCIN, 0, 0, d);  cp[0] = d;
    add(1, NB * NTM * NV * NCM, 0, 0, d);  cp[1] = d;
    add(15, NKC, 0, 0, d);                 cp[15] = d;
    add(7, NC, 0, 0, d);  cp[7] = d;
    add(8, NC, 0, 0, d);  cp[8] = d;
    add(12, NC, 0, 0, d); cp[12] = d;
    add(13, NC, 0, 0, d); cp[13] = d;
    add(16, NC, 0, 0, d); cp[16] = d;
    add(17, NC, 0, 0, d); cp[17] = d;
    ush* w1t;
    add(4, NCIN * NC, NCIN, NC, w1t);      // [256][64] q
    add(5, NCIN * NC, NCIN, NC, d);        // k  (contiguous after q)
    add(6, NCIN * NC, NCIN, NC, d);        // v
    ush* wq2t;
    add(9, NC * NC, NC, NC, wq2t);         // [256][256]
    ush* wkv2t;
    add(10, NCM * NC, NCM, NC, wkv2t);     // [256][256] k
    add(11, NCM * NC, NCM, NC, d);         // v (contiguous)
    ush* wgt;
    add(14, NC * NKC, NC, NKC, wgt);       // [768][256]
    k_convall<<<blk, 256, 0, stream>>>(tab, flag);

    const int M = (int)NTOK;
    // stage 1: qkv1 = x @ [Wq1|Wk1|Wv1]  -> bufA [M,768]
    k_gemm<<<dim3(6, M / 128), 256, 0, stream>>>(cp[0], w1t, bufA, M, NCIN, NKC);
    k_attn_mfma<1><<<dim3(NV, NH / 4, NB), 512, 0, stream>>>(bufA, bufB);
    k_ln<<<M / 4, 256, 0, stream>>>(bufB, cp[7], cp[8]);
    // stage 2 (one launch): q2 = h1@Wq2 (cols 0-255) + kv2 = m@[Wk2|Wv2] (cols 256-767)
    k_gemm_s2<<<dim3(6, M / 128), 256, 0, stream>>>(bufB, cp[1], wq2t, wkv2t, bufA, M);
    k_attn_mfma<0><<<dim3(NV, NH / 4, NB), 512, 0, stream>>>(bufA, bufB);
    k_ln<<<M / 4, 256, 0, stream>>>(bufB, cp[12], cp[13]);
    // stage 3: xw = h2 @ Wg -> bufA [M,768]; then MFMA GCN + LN -> out
    k_gemm<<<dim3(6, M / 128), 256, 0, stream>>>(bufB, wgt, bufA, M, NC, NKC);
    k_gcn_mfma<<<dim3(NT, NB), 256, 0, stream>>>(bufA, A2, cs4, cp[15], cp[16], cp[17],
                                                 (float*)d_out);
}

// Round 21
// 231.029 us; speedup vs baseline: 1.0817x; 1.0096x over previous
//
#include <hip/hip_runtime.h>
#include <hip/hip_bf16.h>

typedef unsigned short ush;
typedef unsigned int uint32;
typedef __attribute__((ext_vector_type(8))) short s8v;   // 8 bf16 (4 VGPRs)
typedef __attribute__((ext_vector_type(4))) float f4v;   // MFMA accumulator

#define NB 16
#define NT 128
#define NTM 128
#define NV 25
#define NCIN 64
#define NCM 256
#define NH 8
#define ND 32
#define NC 256
#define NK 3
#define NKC 768
#define LN_EPS 1e-6f
#define QSCALE 0.17677669529663687f

__device__ __forceinline__ float bf2f(ush u) {
    union { uint32 i; float f; } x; x.i = ((uint32)u) << 16; return x.f;
}
__device__ __forceinline__ ush f2bf(float f) {
    union { float f; uint32 i; } x; x.f = f;
    uint32 r = x.i + 0x7FFFu + ((x.i >> 16) & 1u);
    return (ush)(r >> 16);
}
__device__ __forceinline__ uint32 pack2(float a, float b) {
    return (uint32)f2bf(a) | ((uint32)f2bf(b) << 16);
}

// -------- dtype detector (f32 vs bf16 device buffers) --------
__global__ __launch_bounds__(256) void k_detect(const uint32* __restrict__ xw,
                                               int* __restrict__ flag)
{
    __shared__ int cnt;
    if (threadIdx.x == 0) cnt = 0;
    __syncthreads();
    int c = 0;
    for (int i = 0; i < 4; ++i) {
        uint32 u = xw[threadIdx.x + 256 * i];
        uint32 e = (u >> 7) & 0xFF;
        c += (e >= 100 && e <= 135) ? 1 : 0;
    }
    atomicAdd(&cnt, c);
    __syncthreads();
    if (threadIdx.x == 0) *flag = (cnt > 700) ? 1 : 0;   // 1 = bf16, 0 = f32
}

// A [k][v][w] -> A2 bf16 [32 w][96 kk], kk = k*32+v (pad w>=25, v>=25 with 0)
//             + cs4[w][4]: cs4[w*4+k] = sum_v A[k][v][w]
__global__ __launch_bounds__(256) void k_convA(const void* __restrict__ src,
                                               ush* __restrict__ A2,
                                               float* __restrict__ cs4,
                                               const int* __restrict__ flag)
{
    const bool isbf = (*flag != 0);
    const int tid = threadIdx.x;
    __shared__ float As[1875];
    for (int i = tid; i < 1875; i += 256)
        As[i] = isbf ? bf2f(((const ush*)src)[i]) : ((const float*)src)[i];
    __syncthreads();
    for (int j = tid; j < 32 * 96; j += 256) {
        int w = j / 96, kk = j - w * 96, k = kk >> 5, v = kk & 31;
        float val = (w < NV && v < NV) ? As[k * 625 + v * 25 + w] : 0.f;
        A2[j] = f2bf(val);
    }
    for (int j = tid; j < 100; j += 256) {
        int w = j >> 2, k = j & 3;
        float s = 0.f;
        if (k < 3)
            for (int v = 0; v < NV; ++v) s += As[k * 625 + v * 25 + w];
        cs4[j] = s;
    }
}

// -------- single-launch converter (weights + vectors only) --------
struct CvEnt { const void* src; ush* dst; int n; int K; int N; int blk0; };
struct CvTab { CvEnt e[16]; };

__global__ __launch_bounds__(256) void k_convall(CvTab tab, const int* __restrict__ flag)
{
    const bool isbf = (*flag != 0);
    const int bi = (int)blockIdx.x;
    int ei = 0;
    #pragma unroll
    for (int i = 1; i < 16; ++i) if (bi >= tab.e[i].blk0) ei = i;
    const CvEnt& e = tab.e[ei];
    if (e.K == 0) {
        const int idx = (bi - e.blk0) * 2048 + (int)threadIdx.x * 8;
        if (idx >= e.n) return;
        if (isbf) {
            *(uint4*)&e.dst[idx] = *(const uint4*)((const ush*)e.src + idx);
        } else {
            const float* s = (const float*)e.src + idx;
            uint4 a = *(const uint4*)s;
            uint4 b = *(const uint4*)(s + 4);
            uint4 o;
            o.x = pack2(((float*)&a)[0], ((float*)&a)[1]);
            o.y = pack2(((float*)&a)[2], ((float*)&a)[3]);
            o.z = pack2(((float*)&b)[0], ((float*)&b)[1]);
            o.w = pack2(((float*)&b)[2], ((float*)&b)[3]);
            *(uint4*)&e.dst[idx] = o;
        }
    } else {
        const int s4 = (bi - e.blk0) * 1024 + (int)threadIdx.x * 4;
        if (s4 >= e.n) return;
        const int k = s4 / e.N, n0 = s4 - k * e.N;
        float v0, v1, v2, v3;
        if (isbf) {
            const ush* s = (const ush*)e.src + s4;
            v0 = bf2f(s[0]); v1 = bf2f(s[1]); v2 = bf2f(s[2]); v3 = bf2f(s[3]);
        } else {
            float4 f = *(const float4*)((const float*)e.src + s4);
            v0 = f.x; v1 = f.y; v2 = f.z; v3 = f.w;
        }
        ush* d = e.dst + (size_t)n0 * e.K + k;
        d[0] = f2bf(v0);
        d[e.K] = f2bf(v1);
        d[2 * e.K] = f2bf(v2);
        d[3 * e.K] = f2bf(v3);
    }
}

// XCD-aware bijective swizzle of the linear block index (requires nwg % 8 == 0)
__device__ __forceinline__ void xcd_swz(int& bx, int& by) {
    const int gx = gridDim.x, nwg = gx * gridDim.y;
    int lin = by * gx + bx;
    lin = (lin & 7) * (nwg >> 3) + (lin >> 3);
    bx = lin % gx;
    by = lin / gx;
}

// f32 reg-staged A tile write: same linear LDS layout + pre-swizzled source
// as the global_load_lds path (16B at row*128 + cc*16, src chunk cc^(r&7)).
__device__ __forceinline__ void stage_a_f32(const float* __restrict__ Af, char* AsB,
                                            int m0, int K, int kt, int w, int rl, int cc)
{
    #pragma unroll
    for (int j = 0; j < 4; ++j) {
        const int r = (w * 4 + j) * 8 + rl;
        const int sc = (cc ^ (r & 7)) * 8;
        const float* ga = Af + (size_t)(m0 + r) * K + kt + sc;
        float4 a = *(const float4*)ga;
        float4 b = *(const float4*)(ga + 4);
        uint4 o;
        o.x = pack2(a.x, a.y);
        o.y = pack2(a.z, a.w);
        o.z = pack2(b.x, b.y);
        o.w = pack2(b.z, b.w);
        *(uint4*)(AsB + r * 128 + cc * 16) = o;
    }
}

// -------- MFMA GEMM: C[M, cols n0..] = A[M,K] @ Bt[N,K]^T --------
// AF32: A consumed directly as f32 (reg-staged + converted); else bf16 gload_lds.
template<int AF32>
__global__ __launch_bounds__(256) void k_gemm(
    const void* __restrict__ Av, const ush* __restrict__ Bt, ush* __restrict__ C,
    int M, int K, int ldC)
{
    int bx = blockIdx.x, by = blockIdx.y;
    xcd_swz(bx, by);
    const int n0 = bx * 128, m0 = by * 128;
    const int tid = threadIdx.x, w = tid >> 6, l = tid & 63;
    __shared__ ush As[8192], Bs[8192];
    char* AsB = (char*)As;
    const char* BsB = (const char*)Bs;
    const int rl = l >> 3, cc = l & 7;
    f4v acc[4][4] = {};
    const int wm = w >> 1, wn = w & 1;

    for (int kt = 0; kt < K; kt += 64) {
        __syncthreads();
        #pragma unroll
        for (int j = 0; j < 4; ++j) {
            const int r = (w * 4 + j) * 8 + rl;
            const int sc = (cc ^ (r & 7)) * 8;
            const ush* gb = &Bt[(size_t)(n0 + r) * K + kt + sc];
            __builtin_amdgcn_global_load_lds(
                (const __attribute__((address_space(1))) uint32*)gb,
                (__attribute__((address_space(3))) uint32*)&Bs[(w * 4 + j) * 512], 16, 0, 0);
        }
        if (AF32) {
            stage_a_f32((const float*)Av, AsB, m0, K, kt, w, rl, cc);
        } else {
            const ush* Ab = (const ush*)Av;
            #pragma unroll
            for (int j = 0; j < 4; ++j) {
                const int r = (w * 4 + j) * 8 + rl;
                const int sc = (cc ^ (r & 7)) * 8;
                const ush* ga = &Ab[(size_t)(m0 + r) * K + kt + sc];
                __builtin_amdgcn_global_load_lds(
                    (const __attribute__((address_space(1))) uint32*)ga,
                    (__attribute__((address_space(3))) uint32*)&As[(w * 4 + j) * 512], 16, 0, 0);
            }
        }
        __syncthreads();
        #pragma unroll
        for (int ks = 0; ks < 2; ++ks) {
            const int ko = ks * 64 + (l >> 4) * 16;
            s8v a[4], b[4];
            #pragma unroll
            for (int mi = 0; mi < 4; ++mi) {
                const int ra = wm * 64 + mi * 16 + (l & 15);
                a[mi] = *(const s8v*)(AsB + ra * 128 + (ko ^ ((ra & 7) << 4)));
            }
            #pragma unroll
            for (int ni = 0; ni < 4; ++ni) {
                const int rb = wn * 64 + ni * 16 + (l & 15);
                b[ni] = *(const s8v*)(BsB + rb * 128 + (ko ^ ((rb & 7) << 4)));
            }
            #pragma unroll
            for (int mi = 0; mi < 4; ++mi)
                #pragma unroll
                for (int ni = 0; ni < 4; ++ni)
                    acc[mi][ni] = __builtin_amdgcn_mfma_f32_16x16x32_bf16(a[mi], b[ni],
                                                                          acc[mi][ni], 0, 0, 0);
        }
    }
    const int col = n0 + wn * 64 + (l & 15);
    #pragma unroll
    for (int mi = 0; mi < 4; ++mi) {
        const int row_base = m0 + wm * 64 + mi * 16 + (l >> 4) * 4;
        #pragma unroll
        for (int ni = 0; ni < 4; ++ni)
            #pragma unroll
            for (int r = 0; r < 4; ++r)
                C[(size_t)(row_base + r) * ldC + col + ni * 16] = f2bf(acc[mi][ni][r]);
    }
}

// -------- merged stage-2 GEMM: bx<2 -> q2 = h1@Wq2 (bf16); bx>=2 -> kv2 = m(f32)@Wkv2 --------
__global__ __launch_bounds__(256) void k_gemm_s2(
    const ush* __restrict__ Aq, const float* __restrict__ Amf,
    const ush* __restrict__ Btq, const ush* __restrict__ Btkv,
    ush* __restrict__ C, int M)
{
    int bx = blockIdx.x, by = blockIdx.y;
    xcd_swz(bx, by);
    const bool qbranch = (bx < 2);
    const ush* Bt = qbranch ? (Btq + (size_t)(bx * 128) * NC)
                            : (Btkv + (size_t)((bx - 2) * 128) * NC);
    const int c0 = bx * 128, m0 = by * 128;
    const int K = NC, ldC = NKC;
    const int tid = threadIdx.x, w = tid >> 6, l = tid & 63;
    __shared__ ush As[8192], Bs[8192];
    char* AsB = (char*)As;
    const char* BsB = (const char*)Bs;
    const int rl = l >> 3, cc = l & 7;
    f4v acc[4][4] = {};
    const int wm = w >> 1, wn = w & 1;

    for (int kt = 0; kt < K; kt += 64) {
        __syncthreads();
        #pragma unroll
        for (int j = 0; j < 4; ++j) {
            const int r = (w * 4 + j) * 8 + rl;
            const int sc = (cc ^ (r & 7)) * 8;
            const ush* gb = &Bt[(size_t)r * K + kt + sc];
            __builtin_amdgcn_global_load_lds(
                (const __attribute__((address_space(1))) uint32*)gb,
                (__attribute__((address_space(3))) uint32*)&Bs[(w * 4 + j) * 512], 16, 0, 0);
        }
        if (qbranch) {
            #pragma unroll
            for (int j = 0; j < 4; ++j) {
                const int r = (w * 4 + j) * 8 + rl;
                const int sc = (cc ^ (r & 7)) * 8;
                const ush* ga = &Aq[(size_t)(m0 + r) * K + kt + sc];
                __builtin_amdgcn_global_load_lds(
                    (const __attribute__((address_space(1))) uint32*)ga,
                    (__attribute__((address_space(3))) uint32*)&As[(w * 4 + j) * 512], 16, 0, 0);
            }
        } else {
            stage_a_f32(Amf, AsB, m0, K, kt, w, rl, cc);
        }
        __syncthreads();
        #pragma unroll
        for (int ks = 0; ks < 2; ++ks) {
            const int ko = ks * 64 + (l >> 4) * 16;
            s8v a[4], b[4];
            #pragma unroll
            for (int mi = 0; mi < 4; ++mi) {
                const int ra = wm * 64 + mi * 16 + (l & 15);
                a[mi] = *(const s8v*)(AsB + ra * 128 + (ko ^ ((ra & 7) << 4)));
            }
            #pragma unroll
            for (int ni = 0; ni < 4; ++ni) {
                const int rb = wn * 64 + ni * 16 + (l & 15);
                b[ni] = *(const s8v*)(BsB + rb * 128 + (ko ^ ((rb & 7) << 4)));
            }
            #pragma unroll
            for (int mi = 0; mi < 4; ++mi)
                #pragma unroll
                for (int ni = 0; ni < 4; ++ni)
                    acc[mi][ni] = __builtin_amdgcn_mfma_f32_16x16x32_bf16(a[mi], b[ni],
                                                                          acc[mi][ni], 0, 0, 0);
        }
    }
    const int col = c0 + wn * 64 + (l & 15);
    #pragma unroll
    for (int mi = 0; mi < 4; ++mi) {
        const int row_base = m0 + wm * 64 + mi * 16 + (l >> 4) * 4;
        #pragma unroll
        for (int ni = 0; ni < 4; ++ni)
            #pragma unroll
            for (int r = 0; r < 4; ++r)
                C[(size_t)(row_base + r) * ldC + col + ni * 16] = f2bf(acc[mi][ni][r]);
    }
}

// -------- MFMA attention: 8 waves = 4 heads x 2 t-halves; K AND V in LDS --------
template<int MASKED>
__global__ __launch_bounds__(512) void k_attn_mfma(
    const ush* __restrict__ QKV, ush* __restrict__ O)
{
    const int v = blockIdx.x, hq = blockIdx.y, b = blockIdx.z;
    const int tid = threadIdx.x, wv = tid >> 6, l = tid & 63;
    const int hs = wv >> 1, th = wv & 1;
    const int h = hq * 4 + hs;
    const int g = l >> 4, c = l & 15;
    __shared__ ush Vs[4][NT * ND];   // 32 KB linear V
    __shared__ ush Ks[4][NT * ND];   // 32 KB swizzled K
    const size_t tokStride = (size_t)NV * NKC;
    const ush* base = QKV + ((size_t)b * NT * NV + v) * NKC;

    const int vrow = l >> 2, vch = (l & 3) * 8;
    #pragma unroll
    for (int i = 0; i < 4; ++i) {
        const int row = 16 * (4 * th + i) + vrow;
        s8v rv = *(const s8v*)(base + (size_t)row * tokStride + 512 + h * ND + vch);
        *(s8v*)&Vs[hs][row * ND + vch] = rv;
        s8v rk = *(const s8v*)(base + (size_t)row * tokStride + 256 + h * ND + vch);
        const uint32 kb = ((uint32)(row * 64 + (l & 3) * 16)) ^ (((uint32)(row & 7)) << 4);
        *(s8v*)((char*)Ks[hs] + kb) = rk;
    }
    __syncthreads();
    s8v vf[4][2];
    #pragma unroll
    for (int ks = 0; ks < 4; ++ks)
        #pragma unroll
        for (int ni = 0; ni < 2; ++ni) {
            s8v tmp;
            #pragma unroll
            for (int j = 0; j < 8; ++j)
                tmp[j] = (short)Vs[hs][(32 * ks + 8 * g + j) * ND + 16 * ni + c];
            vf[ks][ni] = tmp;
        }

    ush* og = O + ((size_t)b * NT * NV + v) * NC + h * ND;
    const int qoff = h * ND + g * 8;
    const int ga = (g & 1) * 2;
    const int l1 = ga * 16 + c, l2 = l1 + 16;
    const bool hisel = (g >> 1) != 0;
    const char* KsB = (const char*)Ks[hs];

    for (int i = 0; i < 4; ++i) {
        const int t16 = 4 * th + i;
        s8v qf = *(const s8v*)(base + (size_t)(16 * t16 + c) * tokStride + qoff);
        f4v st[8];
        #pragma unroll
        for (int si = 0; si < 8; ++si) {
            if (MASKED && si > t16) { st[si] = (f4v){0.f, 0.f, 0.f, 0.f}; continue; }
            const int krow = 16 * si + c;
            const uint32 rb = ((uint32)(krow * 64 + g * 16)) ^ (((uint32)(krow & 7)) << 4);
            s8v kf = *(const s8v*)(KsB + rb);
            st[si] = __builtin_amdgcn_mfma_f32_16x16x32_bf16(kf, qf,
                                                             (f4v){0.f, 0.f, 0.f, 0.f}, 0, 0, 0);
        }
        const int t = 16 * t16 + c;
        if (MASKED) {
            #pragma unroll
            for (int si = 0; si < 8; ++si) {
                if (si > t16) continue;
                #pragma unroll
                for (int r = 0; r < 4; ++r)
                    if (16 * si + 4 * g + r > t) st[si][r] = -1e30f;
            }
        }
        float mx = -1e30f;
        #pragma unroll
        for (int si = 0; si < 8; ++si) {
            if (MASKED && si > t16) continue;
            #pragma unroll
            for (int r = 0; r < 4; ++r) mx = fmaxf(mx, st[si][r]);
        }
        mx = fmaxf(mx, __shfl_xor(mx, 16));
        mx = fmaxf(mx, __shfl_xor(mx, 32));
        float sm = 0.f;
        #pragma unroll
        for (int si = 0; si < 8; ++si) {
            if (MASKED && si > t16) continue;
            #pragma unroll
            for (int r = 0; r < 4; ++r) {
                float e = __expf((st[si][r] - mx) * QSCALE);
                st[si][r] = e;
                sm += e;
            }
        }
        sm += __shfl_xor(sm, 16);
        sm += __shfl_xor(sm, 32);
        const float inv = 1.f / sm;
        uint32 u[8][2];
        #pragma unroll
        for (int si = 0; si < 8; ++si) {
            if (MASKED && si > t16) { u[si][0] = 0u; u[si][1] = 0u; continue; }
            float e0 = st[si][0] * inv, e1 = st[si][1] * inv;
            float e2 = st[si][2] * inv, e3 = st[si][3] * inv;
            asm("v_cvt_pk_bf16_f32 %0, %1, %2" : "=v"(u[si][0]) : "v"(e0), "v"(e1));
            asm("v_cvt_pk_bf16_f32 %0, %1, %2" : "=v"(u[si][1]) : "v"(e2), "v"(e3));
        }
        f4v o[2] = {};
        #pragma unroll
        for (int ks = 0; ks < 4; ++ks) {
            if (MASKED && 2 * ks > t16) continue;
            uint32 w0a = __shfl(u[2 * ks][0], l1),     w0b = __shfl(u[2 * ks][1], l1);
            uint32 w0c = __shfl(u[2 * ks][0], l2),     w0d = __shfl(u[2 * ks][1], l2);
            uint32 w1a = __shfl(u[2 * ks + 1][0], l1), w1b = __shfl(u[2 * ks + 1][1], l1);
            uint32 w1c = __shfl(u[2 * ks + 1][0], l2), w1d = __shfl(u[2 * ks + 1][1], l2);
            union { uint32 w[4]; s8v s; } pa;
            pa.w[0] = hisel ? w1a : w0a;
            pa.w[1] = hisel ? w1b : w0b;
            pa.w[2] = hisel ? w1c : w0c;
            pa.w[3] = hisel ? w1d : w0d;
            o[0] = __builtin_amdgcn_mfma_f32_16x16x32_bf16(pa.s, vf[ks][0], o[0], 0, 0, 0);
            o[1] = __builtin_amdgcn_mfma_f32_16x16x32_bf16(pa.s, vf[ks][1], o[1], 0, 0, 0);
        }
        #pragma unroll
        for (int ni = 0; ni < 2; ++ni)
            #pragma unroll
            for (int r = 0; r < 4; ++r)
                og[(size_t)(16 * t16 + 4 * g + r) * (NV * NC) + 16 * ni + c] = f2bf(o[ni][r]);
    }
}

// ---------------- row LayerNorm (unbiased std), in place, 1 wave = 1 row ----------------
__global__ __launch_bounds__(256) void k_ln(
    ush* __restrict__ buf, const ush* __restrict__ g, const ush* __restrict__ bb)
{
    const int row = blockIdx.x * 4 + (threadIdx.x >> 6);
    const int lane = threadIdx.x & 63;
    ush* p = buf + (size_t)row * NC + lane * 4;
    uint2 u = *(uint2*)p;
    float x0 = bf2f((ush)(u.x & 0xffff)), x1 = bf2f((ush)(u.x >> 16));
    float x2 = bf2f((ush)(u.y & 0xffff)), x3 = bf2f((ush)(u.y >> 16));
    float s = x0 + x1 + x2 + x3;
    float q = x0 * x0 + x1 * x1 + x2 * x2 + x3 * x3;
    #pragma unroll
    for (int o = 32; o; o >>= 1) { s += __shfl_xor(s, o); q += __shfl_xor(q, o); }
    float mean = s * (1.f / 256.f);
    float var = fmaxf((q - 256.f * mean * mean) * (1.f / 255.f), 0.f);
    float inv = 1.f / (sqrtf(var) + LN_EPS);
    float o0 = bf2f(g[lane * 4 + 0]) * (x0 - mean) * inv + bf2f(bb[lane * 4 + 0]);
    float o1 = bf2f(g[lane * 4 + 1]) * (x1 - mean) * inv + bf2f(bb[lane * 4 + 1]);
    float o2 = bf2f(g[lane * 4 + 2]) * (x2 - mean) * inv + bf2f(bb[lane * 4 + 2]);
    float o3 = bf2f(g[lane * 4 + 3]) * (x3 - mean) * inv + bf2f(bb[lane * 4 + 3]);
    uint32 lo = pack2(o0, o1);
    uint32 hi = pack2(o2, o3);
    *(uint2*)p = make_uint2(lo, hi);
}

// -------- GCN via MFMA: per (b,t): h3[32 w][256 c] = A2[32][96] @ X[96][256] --------
__global__ __launch_bounds__(256) void k_gcn_mfma(
    const ush* __restrict__ xw, const ush* __restrict__ A2,
    const float* __restrict__ cs4,
    const ush* __restrict__ bg, const ush* __restrict__ g3, const ush* __restrict__ b3,
    float* __restrict__ outp)
{
    const int t = blockIdx.x, b = blockIdx.y;
    const int tid = threadIdx.x;
    __shared__ uint4 Xs4[2400];                 // 38.4KB: X tile, swizzled
    char* Xs = (char*)Xs4;
    float* h3s = (float*)Xs4;                   // [25][260] f32 overlay after barrier
    const int l = tid & 63, wv = tid >> 6, g = l >> 4, c4 = l & 15;

    s8v af[2][3];
    #pragma unroll
    for (int mi = 0; mi < 2; ++mi)
        #pragma unroll
        for (int ks = 0; ks < 3; ++ks)
            af[mi][ks] = *(const s8v*)&A2[(mi * 16 + c4) * 96 + ks * 32 + g * 8];

    const ush* xr = xw + ((size_t)(b * NT + t)) * NV * NKC;
    for (int i = tid; i < 2400; i += 256) {
        int v = i / 96, c8 = i - v * 96;
        uint32 off = (uint32)(v * 1536 + c8 * 16) ^ (((v >> 3) & 3) << 4);
        *(uint4*)(Xs + off) = *(const uint4*)&xr[(size_t)v * NKC + c8 * 8];
    }
    __syncthreads();

    f4v acc[2][4] = {};
    const int c0 = wv * 64;
    #pragma unroll
    for (int ks = 0; ks < 3; ++ks) {
        #pragma unroll
        for (int ni = 0; ni < 4; ++ni) {
            const int c = c0 + ni * 16 + c4;
            s8v bfr;
            #pragma unroll
            for (int j = 0; j < 8; ++j) {
                int v = g * 8 + j; if (v > 24) v = 24;
                uint32 off = (uint32)(v * 1536 + ks * 512 + c * 2) ^ (((v >> 3) & 3) << 4);
                bfr[j] = *(const short*)(Xs + off);
            }
            acc[0][ni] = __builtin_amdgcn_mfma_f32_16x16x32_bf16(af[0][ks], bfr, acc[0][ni], 0, 0, 0);
            acc[1][ni] = __builtin_amdgcn_mfma_f32_16x16x32_bf16(af[1][ks], bfr, acc[1][ni], 0, 0, 0);
        }
    }
    __syncthreads();
    #pragma unroll
    for (int mi = 0; mi < 2; ++mi)
        #pragma unroll
        for (int r = 0; r < 4; ++r) {
            const int w = mi * 16 + g * 4 + r;
            if (w < NV) {
                #pragma unroll
                for (int ni = 0; ni < 4; ++ni)
                    h3s[w * 260 + c0 + ni * 16 + c4] = acc[mi][ni][r];
            }
        }
    __syncthreads();
    {
        const int lane = tid & 63;
        float bgq[3][4];
        #pragma unroll
        for (int k = 0; k < 3; ++k)
            #pragma unroll
            for (int i = 0; i < 4; ++i)
                bgq[k][i] = bf2f(bg[k * NC + lane * 4 + i]);
        for (int w = wv; w < NV; w += 4) {
            float4 xq = *(const float4*)&h3s[w * 260 + lane * 4];
            const float cw0 = cs4[w * 4], cw1 = cs4[w * 4 + 1], cw2 = cs4[w * 4 + 2];
            xq.x += cw0 * bgq[0][0] + cw1 * bgq[1][0] + cw2 * bgq[2][0];
            xq.y += cw0 * bgq[0][1] + cw1 * bgq[1][1] + cw2 * bgq[2][1];
            xq.z += cw0 * bgq[0][2] + cw1 * bgq[1][2] + cw2 * bgq[2][2];
            xq.w += cw0 * bgq[0][3] + cw1 * bgq[1][3] + cw2 * bgq[2][3];
            float s = xq.x + xq.y + xq.z + xq.w;
            float q = xq.x * xq.x + xq.y * xq.y + xq.z * xq.z + xq.w * xq.w;
            #pragma unroll
            for (int o = 32; o; o >>= 1) { s += __shfl_xor(s, o); q += __shfl_xor(q, o); }
            float mean = s * (1.f / 256.f);
            float var = fmaxf((q - 256.f * mean * mean) * (1.f / 255.f), 0.f);
            float inv = 1.f / (sqrtf(var) + LN_EPS);
            float o0 = bf2f(g3[lane * 4 + 0]) * (xq.x - mean) * inv + bf2f(b3[lane * 4 + 0]);
            float o1 = bf2f(g3[lane * 4 + 1]) * (xq.y - mean) * inv + bf2f(b3[lane * 4 + 1]);
            float o2 = bf2f(g3[lane * 4 + 2]) * (xq.z - mean) * inv + bf2f(b3[lane * 4 + 2]);
            float o3 = bf2f(g3[lane * 4 + 3]) * (xq.w - mean) * inv + bf2f(b3[lane * 4 + 3]);
            float* op = outp + (((size_t)(b * NT + t)) * NV + w) * NC + lane * 4;
            *(float4*)op = make_float4(o0, o1, o2, o3);
        }
    }
}

extern "C" void kernel_launch(void* const* d_in, const int* in_sizes, int n_in,
                              void* d_out, int out_size, void* d_ws, size_t ws_size,
                              hipStream_t stream)
{
    const size_t NTOK = (size_t)NB * NT * NV;   // 51200
    char* ws = (char*)d_ws;
    int* flag = (int*)ws;
    ush* A2 = (ush*)(ws + 256);                 // [32][96] bf16, 6KB
    float* cs4 = (float*)(ws + 256 + 6144);     // [25][4] f32, 400B
    ush* bufA = (ush*)(ws + 16384);             // [M,768]  78.6MB
    ush* bufB = bufA + NTOK * NKC;              // [M,256]  26.2MB
    ush* conv = bufB + NTOK * NC;

    k_detect<<<1, 256, 0, stream>>>((const uint32*)d_in[0], flag);
    k_convA<<<1, 256, 0, stream>>>(d_in[2], A2, cs4, flag);

    // ---- one-launch conversion table (weights + LN vectors only) ----
    CvTab tab;
    for (int i = 0; i < 16; ++i) tab.e[i] = { nullptr, nullptr, 0, 0, 0, 0x7fffffff };
    int nent = 0, blk = 0;
    ush* p = conv;
    const ush* cp[18] = {};
    auto add = [&](int idx, int n, int K, int N, ush*& dst_out) {
        tab.e[nent] = { d_in[idx], p, n, K, N, blk };
        dst_out = p;
        blk += (K == 0) ? (n + 2047) / 2048 : (n + 1023) / 1024;
        p += (size_t)((n + 7) & ~7);
        ++nent;
    };
    ush* d;
    add(15, NKC, 0, 0, d);                 cp[15] = d;
    add(7, NC, 0, 0, d);  cp[7] = d;
    add(8, NC, 0, 0, d);  cp[8] = d;
    add(12, NC, 0, 0, d); cp[12] = d;
    add(13, NC, 0, 0, d); cp[13] = d;
    add(16, NC, 0, 0, d); cp[16] = d;
    add(17, NC, 0, 0, d); cp[17] = d;
    ush* w1t;
    add(4, NCIN * NC, NCIN, NC, w1t);      // [256][64] q
    add(5, NCIN * NC, NCIN, NC, d);        // k  (contiguous after q)
    add(6, NCIN * NC, NCIN, NC, d);        // v
    ush* wq2t;
    add(9, NC * NC, NC, NC, wq2t);         // [256][256]
    ush* wkv2t;
    add(10, NCM * NC, NCM, NC, wkv2t);     // [256][256] k
    add(11, NCM * NC, NCM, NC, d);         // v (contiguous)
    ush* wgt;
    add(14, NC * NKC, NC, NKC, wgt);       // [768][256]
    k_convall<<<blk, 256, 0, stream>>>(tab, flag);

    const int M = (int)NTOK;
    // stage 1: qkv1 = x(f32) @ [Wq1|Wk1|Wv1]  -> bufA [M,768]
    k_gemm<1><<<dim3(6, M / 128), 256, 0, stream>>>(d_in[0], w1t, bufA, M, NCIN, NKC);
    k_attn_mfma<1><<<dim3(NV, NH / 4, NB), 512, 0, stream>>>(bufA, bufB);
    k_ln<<<M / 4, 256, 0, stream>>>(bufB, cp[7], cp[8]);
    // stage 2 (one launch): q2 = h1@Wq2 (cols 0-255) + kv2 = m(f32)@[Wk2|Wv2] (cols 256-767)
    k_gemm_s2<<<dim3(6, M / 128), 256, 0, stream>>>(bufB, (const float*)d_in[1],
                                                    wq2t, wkv2t, bufA, M);
    k_attn_mfma<0><<<dim3(NV, NH / 4, NB), 512, 0, stream>>>(bufA, bufB);
    k_ln<<<M / 4, 256, 0, stream>>>(bufB, cp[12], cp[13]);
    // stage 3: xw = h2 @ Wg -> bufA [M,768]; then MFMA GCN + LN -> out
    k_gemm<0><<<dim3(6, M / 128), 256, 0, stream>>>(bufB, wgt, bufA, M, NC, NKC);
    k_gcn_mfma<<<dim3(NT, NB), 256, 0, stream>>>(bufA, A2, cs4, cp[15], cp[16], cp[17],
                                                 (float*)d_out);
}